// Round 9
// baseline (389.622 us; speedup 1.0000x reference)
//
#include <hip/hip_runtime.h>
#include <math.h>

// Problem constants
#define N_NODES 50000
#define N_EDGES 800000
#define IN_CH 128
#define HID 256
#define OUT_CH 40
#define GRP 6250          // nodes per dst-group (8 groups)

typedef unsigned short u16;
typedef unsigned char u8;
typedef __attribute__((ext_vector_type(8))) short bf16x8;
typedef __attribute__((ext_vector_type(4))) float f32x4;
typedef __attribute__((ext_vector_type(2))) float f32x2;

__device__ __forceinline__ float bf2f(u16 u) {
    union { unsigned int i; float f; } v; v.i = ((unsigned int)u) << 16; return v.f;
}
__device__ __forceinline__ u16 f2bf(float f) {   // round-to-nearest-even
    union { float f; unsigned int i; } v; v.f = f;
    unsigned int x = v.i;
    x += 0x7fffu + ((x >> 16) & 1u);
    return (u16)(x >> 16);
}

#define GLOBAL_AS __attribute__((address_space(1)))
#define LDS_AS __attribute__((address_space(3)))
__device__ __forceinline__ void async_cp16(const void* g, void* l) {
    __builtin_amdgcn_global_load_lds((const GLOBAL_AS unsigned int*)g,
                                     (LDS_AS unsigned int*)l, 16, 0, 0);
}

// ===========================================================================
// Fused prep: privatized degree histogram + x->{bf16,fp8} + weight transposes.
// Block ranges:
//   [0,128)        histogram: 8 dst-groups x 16 edge-chunks, LDS-privatized,
//                  non-atomic partial writes (partial[sub*8+g][i])
//   [128,6378)     conv_x  (1.6M float4 / 256)
//   [6378,7530)    transposes (1152 output rows)
// ===========================================================================
__device__ __forceinline__ void tr_one(
    const float* __restrict__ in, u16* __restrict__ out, int K, int N, int n)
{
    for (int k = threadIdx.x; k < K; k += 256) {
        float v = (n < N) ? in[(size_t)k * N + n] : 0.f;
        out[(size_t)n * K + k] = f2bf(v);
    }
}

__global__ __launch_bounds__(256) void prep_fused(
    const int* __restrict__ ei, int* __restrict__ partial,
    const float* __restrict__ x, u16* __restrict__ xb, u8* __restrict__ xf8,
    const float* __restrict__ W1a, const float* __restrict__ W2a,
    const float* __restrict__ W1b, const float* __restrict__ W2b,
    const float* __restrict__ Wlin,
    u16* __restrict__ W1aT, u16* __restrict__ W2aT,
    u16* __restrict__ W1bT, u16* __restrict__ W2bT, u16* __restrict__ WlinT)
{
    __shared__ int hist[GRP];     // 25 KB; only the 128 hist blocks use it
    int b = blockIdx.x;
    if (b < 128) {
        const int g = b & 7;          // dst-group
        const int sub = b >> 3;       // edge-chunk 0..15
        const int lo = g * GRP;
        for (int i = threadIdx.x; i < GRP; i += 256) hist[i] = 0;
        __syncthreads();
        const int* dsts = ei + N_EDGES + sub * 50000;
        for (int k = threadIdx.x; k < 50000; k += 256) {
            int r = dsts[k] - lo;
            if ((unsigned)r < (unsigned)GRP) atomicAdd(&hist[r], 1);
        }
        __syncthreads();
        int* po = partial + (size_t)b * GRP;
        for (int i = threadIdx.x; i < GRP; i += 256) po[i] = hist[i];
    } else if (b < 6378) {
        int i = (b - 128) * 256 + threadIdx.x;
        float4 v = ((const float4*)x)[i];
        ushort4 o;
        o.x = f2bf(v.x); o.y = f2bf(v.y); o.z = f2bf(v.z); o.w = f2bf(v.w);
        ((ushort4*)xb)[i] = o;
        int p = __builtin_amdgcn_cvt_pk_fp8_f32(v.x, v.y, 0, false);
        p = __builtin_amdgcn_cvt_pk_fp8_f32(v.z, v.w, p, true);
        ((unsigned int*)xf8)[i] = (unsigned int)p;
    } else {
        int t = b - 6378;
        if (t < 256)       tr_one(W1a, W1aT, IN_CH, HID, t);
        else if (t < 512)  tr_one(W2a, W2aT, HID, HID, t - 256);
        else if (t < 768)  tr_one(W1b, W1bT, HID, HID, t - 512);
        else if (t < 1024) tr_one(W2b, W2bT, HID, HID, t - 768);
        else               tr_one(Wlin, WlinT, 2 * HID, OUT_CH, t - 1024);
    }
}

// ===========================================================================
// scan1: per-node degree = sum of 16 partials; block-scan 1024 nodes.
// ===========================================================================
__global__ __launch_bounds__(256) void scan1(
    const int* __restrict__ partial, int* __restrict__ excl,
    int* __restrict__ partials_out)
{
    __shared__ int lds[256];
    const int tid = threadIdx.x;
    const int base = blockIdx.x * 1024 + tid * 4;
    int v[4]; int s = 0;
#pragma unroll
    for (int i = 0; i < 4; i++) {
        int idx = base + i;
        int d = 0;
        if (idx < N_NODES) {
            int g = idx / GRP;
            int off = idx - g * GRP;
#pragma unroll
            for (int sub = 0; sub < 16; sub++)
                d += partial[(size_t)(sub * 8 + g) * GRP + off];
        }
        v[i] = d;
        s += d;
    }
    lds[tid] = s;
    __syncthreads();
    for (int off = 1; off < 256; off <<= 1) {
        int t = (tid >= off) ? lds[tid - off] : 0;
        __syncthreads();
        lds[tid] += t;
        __syncthreads();
    }
    int run = lds[tid] - s;
#pragma unroll
    for (int i = 0; i < 4; i++) {
        int idx = base + i;
        if (idx < N_NODES) excl[idx] = run;
        run += v[i];
    }
    if (tid == 255) partials_out[blockIdx.x] = lds[255];
}

// scan3: each block wave-scans the 49 block partials itself, adds offsets.
__global__ __launch_bounds__(256) void scan3(
    int* __restrict__ excl, const int* __restrict__ partials,
    int* __restrict__ cursor, int nPart)
{
    __shared__ int bp[64];
    const int tid = threadIdx.x;
    if (tid < 64) {
        int orig = (tid < nPart) ? partials[tid] : 0;
        int v = orig;
#pragma unroll
        for (int off = 1; off < 64; off <<= 1) {
            int t = __shfl_up(v, off, 64);
            if (tid >= off) v += t;
        }
        bp[tid] = v - orig;
    }
    __syncthreads();
    int idx = blockIdx.x * 256 + tid;
    if (idx < N_NODES) {
        int r = excl[idx] + bp[idx >> 10];
        excl[idx] = r;
        cursor[idx] = r;
    }
}

// Dst-sharded fill: group g = blockIdx&7 handles dst in [g*GRP,(g+1)*GRP).
__global__ __launch_bounds__(256) void csr_fill(
    const int* __restrict__ ei, int* __restrict__ cursor, u16* __restrict__ csr_src)
{
    const int g = blockIdx.x & 7;
    const int c = blockIdx.x >> 3;
    const int lo = g * GRP, hi = lo + GRP;
    const int base = c * 2048;
#pragma unroll
    for (int i = 0; i < 8; i++) {
        int e = base + i * 256 + threadIdx.x;
        if (e < N_EDGES) {
            int s = ei[e];
            int d = ei[N_EDGES + e];
            if (d >= lo && d < hi) {
                int pos = atomicAdd(&cursor[d], 1);
                csr_src[pos] = (u16)s;
            }
        }
    }
}

// ===========================================================================
// Gather aggregation, fp8 neighbor table + bf16 self term, fp32 accumulate:
//   out[n] = feat_bf[n] + sum_{e in row n} fp8(feat[src[e]])
// One 64-lane wave per node; 4-deep unroll for MLP.
// ===========================================================================
__global__ __launch_bounds__(256) void gather_agg_f8_128(
    const u16* __restrict__ feat_bf, const u8* __restrict__ feat_f8,
    const int* __restrict__ row_ptr, const int* __restrict__ row_end,
    const u16* __restrict__ csr_src, u16* __restrict__ out)
{
    int node = (blockIdx.x * 256 + threadIdx.x) >> 6;
    int lane = threadIdx.x & 63;
    if (node >= N_NODES) return;
    ushort2 sv = ((const ushort2*)(feat_bf + (size_t)node * IN_CH))[lane];
    float ax = bf2f(sv.x), ay = bf2f(sv.y);
    int j = row_ptr[node], e = row_end[node];
    for (; j + 4 <= e; j += 4) {
        int s0 = csr_src[j], s1 = csr_src[j + 1];
        int s2 = csr_src[j + 2], s3 = csr_src[j + 3];
        int v0 = ((const u16*)(feat_f8 + (size_t)s0 * IN_CH))[lane];
        int v1 = ((const u16*)(feat_f8 + (size_t)s1 * IN_CH))[lane];
        int v2 = ((const u16*)(feat_f8 + (size_t)s2 * IN_CH))[lane];
        int v3 = ((const u16*)(feat_f8 + (size_t)s3 * IN_CH))[lane];
        f32x2 d0 = __builtin_amdgcn_cvt_pk_f32_fp8(v0, false);
        f32x2 d1 = __builtin_amdgcn_cvt_pk_f32_fp8(v1, false);
        f32x2 d2 = __builtin_amdgcn_cvt_pk_f32_fp8(v2, false);
        f32x2 d3 = __builtin_amdgcn_cvt_pk_f32_fp8(v3, false);
        ax += (d0.x + d1.x) + (d2.x + d3.x);
        ay += (d0.y + d1.y) + (d2.y + d3.y);
    }
    for (; j < e; j++) {
        int sa = csr_src[j];
        int va = ((const u16*)(feat_f8 + (size_t)sa * IN_CH))[lane];
        f32x2 da = __builtin_amdgcn_cvt_pk_f32_fp8(va, false);
        ax += da.x; ay += da.y;
    }
    ushort2 o; o.x = f2bf(ax); o.y = f2bf(ay);
    ((ushort2*)(out + (size_t)node * IN_CH))[lane] = o;
}

__global__ __launch_bounds__(256) void gather_agg_f8_256(
    const u16* __restrict__ feat_bf, const u8* __restrict__ feat_f8,
    const int* __restrict__ row_ptr, const int* __restrict__ row_end,
    const u16* __restrict__ csr_src, u16* __restrict__ out)
{
    int node = (blockIdx.x * 256 + threadIdx.x) >> 6;
    int lane = threadIdx.x & 63;
    if (node >= N_NODES) return;
    ushort4 sv = ((const ushort4*)(feat_bf + (size_t)node * HID))[lane];
    float ax = bf2f(sv.x), ay = bf2f(sv.y), az = bf2f(sv.z), aw = bf2f(sv.w);
    int j = row_ptr[node], e = row_end[node];
    for (; j + 4 <= e; j += 4) {
        int s0 = csr_src[j], s1 = csr_src[j + 1];
        int s2 = csr_src[j + 2], s3 = csr_src[j + 3];
        int v0 = ((const int*)(feat_f8 + (size_t)s0 * HID))[lane];
        int v1 = ((const int*)(feat_f8 + (size_t)s1 * HID))[lane];
        int v2 = ((const int*)(feat_f8 + (size_t)s2 * HID))[lane];
        int v3 = ((const int*)(feat_f8 + (size_t)s3 * HID))[lane];
        f32x2 l0 = __builtin_amdgcn_cvt_pk_f32_fp8(v0, false);
        f32x2 h0 = __builtin_amdgcn_cvt_pk_f32_fp8(v0, true);
        f32x2 l1 = __builtin_amdgcn_cvt_pk_f32_fp8(v1, false);
        f32x2 h1v = __builtin_amdgcn_cvt_pk_f32_fp8(v1, true);
        f32x2 l2 = __builtin_amdgcn_cvt_pk_f32_fp8(v2, false);
        f32x2 h2v = __builtin_amdgcn_cvt_pk_f32_fp8(v2, true);
        f32x2 l3 = __builtin_amdgcn_cvt_pk_f32_fp8(v3, false);
        f32x2 h3 = __builtin_amdgcn_cvt_pk_f32_fp8(v3, true);
        ax += (l0.x + l1.x) + (l2.x + l3.x);
        ay += (l0.y + l1.y) + (l2.y + l3.y);
        az += (h0.x + h1v.x) + (h2v.x + h3.x);
        aw += (h0.y + h1v.y) + (h2v.y + h3.y);
    }
    for (; j < e; j++) {
        int sa = csr_src[j];
        int va = ((const int*)(feat_f8 + (size_t)sa * HID))[lane];
        f32x2 la = __builtin_amdgcn_cvt_pk_f32_fp8(va, false);
        f32x2 ha = __builtin_amdgcn_cvt_pk_f32_fp8(va, true);
        ax += la.x; ay += la.y; az += ha.x; aw += ha.y;
    }
    ushort4 o;
    o.x = f2bf(ax); o.y = f2bf(ay); o.z = f2bf(az); o.w = f2bf(aw);
    ((ushort4*)(out + (size_t)node * HID))[lane] = o;
}

// ===========================================================================
// bf16 MFMA GEMM (m97 structure, BK=32): out = act(Aeff[M,K] @ BT^T + bias)
// outF8 != null: additionally store e4m3 copy (fp8 neighbor table for gather).
// ===========================================================================
__global__ __launch_bounds__(256, 3) void gemm_mfma(
    const u16* __restrict__ A, const u16* __restrict__ Acat, int Ksplit, int ldA,
    const u16* __restrict__ BT, const float* __restrict__ bias,
    void* __restrict__ out, u8* __restrict__ outF8,
    int M, int Nreal, int K, int relu, int ldOut, int fuseLS)
{
    __shared__ u16 As[128 * 32];
    __shared__ u16 Bs[128 * 32];

    const int tid = threadIdx.x;
    const int lane = tid & 63;
    const int wid = tid >> 6;
    const int wm = wid >> 1, wn = wid & 1;
    const int row0 = blockIdx.y * 128;
    const int col0 = blockIdx.x * 128;

    f32x4 acc[4][4];
#pragma unroll
    for (int i = 0; i < 4; i++)
#pragma unroll
        for (int j = 0; j < 4; j++) acc[i][j] = (f32x4){0.f, 0.f, 0.f, 0.f};

    for (int kk = 0; kk < K; kk += 32) {
        const u16* Abase = (Acat != nullptr && kk >= Ksplit) ? Acat : A;
        const int kbase = (Acat != nullptr && kk >= Ksplit) ? (kk - Ksplit) : kk;
#pragma unroll
        for (int i = 0; i < 2; i++) {
            int chunk = i * 256 + tid;
            int r = chunk >> 2, c = chunk & 3;
            int grow = row0 + r; if (grow > M - 1) grow = M - 1;
            async_cp16(Abase + (size_t)grow * ldA + kbase + c * 8, As + chunk * 8);
        }
#pragma unroll
        for (int i = 0; i < 2; i++) {
            int chunk = i * 256 + tid;
            int r = chunk >> 2, c = chunk & 3;
            async_cp16(BT + (size_t)(col0 + r) * K + kk + c * 8, Bs + chunk * 8);
        }
        __syncthreads();

        const int koff = (lane >> 4) * 8;
        const int am = wm * 64 + (lane & 15);
        const int bn = wn * 64 + (lane & 15);
        bf16x8 af[4], bfr[4];
#pragma unroll
        for (int t = 0; t < 4; t++) {
            af[t]  = *(const bf16x8*)(As + (am + t * 16) * 32 + koff);
            bfr[t] = *(const bf16x8*)(Bs + (bn + t * 16) * 32 + koff);
        }
#pragma unroll
        for (int mt = 0; mt < 4; mt++)
#pragma unroll
            for (int nt = 0; nt < 4; nt++)
                acc[mt][nt] = __builtin_amdgcn_mfma_f32_16x16x32_bf16(
                    af[mt], bfr[nt], acc[mt][nt], 0, 0, 0);
        __syncthreads();
    }

    if (fuseLS) {
        if (wn != 0) return;
        const int quad = lane >> 4, li = lane & 15;
        float b0 = bias[li];
        float b1 = bias[16 + li];
        float b2 = (li < 8) ? bias[32 + li] : 0.f;
        float* o = (float*)out;
#pragma unroll
        for (int mt = 0; mt < 4; mt++) {
#pragma unroll
            for (int reg = 0; reg < 4; reg++) {
                int row = row0 + wm * 64 + mt * 16 + quad * 4 + reg;
                float v0 = acc[mt][0][reg] + b0;
                float v1 = acc[mt][1][reg] + b1;
                float v2 = (li < 8) ? (acc[mt][2][reg] + b2) : -INFINITY;
                float m = fmaxf(fmaxf(v0, v1), v2);
#pragma unroll
                for (int off = 1; off < 16; off <<= 1)
                    m = fmaxf(m, __shfl_xor(m, off, 64));
                float s = expf(v0 - m) + expf(v1 - m)
                        + ((li < 8) ? expf(v2 - m) : 0.f);
#pragma unroll
                for (int off = 1; off < 16; off <<= 1)
                    s += __shfl_xor(s, off, 64);
                float lg = m + logf(s);
                if (row < M) {
                    o[(size_t)row * OUT_CH + li] = v0 - lg;
                    o[(size_t)row * OUT_CH + 16 + li] = v1 - lg;
                    if (li < 8) o[(size_t)row * OUT_CH + 32 + li] = v2 - lg;
                }
            }
        }
        return;
    }

#pragma unroll
    for (int nt = 0; nt < 4; nt++) {
        int col = col0 + wn * 64 + nt * 16 + (lane & 15);
        bool colOk = (col < Nreal);
        float bv = colOk ? bias[col] : 0.f;
#pragma unroll
        for (int mt = 0; mt < 4; mt++) {
            int rbase = row0 + wm * 64 + mt * 16 + ((lane >> 4) << 2);
#pragma unroll
            for (int reg = 0; reg < 4; reg++) {
                int row = rbase + reg;
                if (colOk && row < M) {
                    float v = acc[mt][nt][reg] + bv;
                    if (relu) v = fmaxf(v, 0.f);
                    ((u16*)out)[(size_t)row * ldOut + col] = f2bf(v);
                    if (outF8 != nullptr) {
                        int pk = __builtin_amdgcn_cvt_pk_fp8_f32(v, v, 0, false);
                        outF8[(size_t)row * ldOut + col] = (u8)(pk & 0xff);
                    }
                }
            }
        }
    }
}

// ---------------------------------------------------------------------------
extern "C" void kernel_launch(void* const* d_in, const int* in_sizes, int n_in,
                              void* d_out, int out_size, void* d_ws, size_t ws_size,
                              hipStream_t stream)
{
    const float* x    = (const float*)d_in[0];
    const int*   ei   = (const int*)d_in[1];
    const float* W1a  = (const float*)d_in[2];
    const float* b1a  = (const float*)d_in[3];
    const float* W2a  = (const float*)d_in[4];
    const float* b2a  = (const float*)d_in[5];
    const float* W1b  = (const float*)d_in[6];
    const float* b1b  = (const float*)d_in[7];
    const float* W2b  = (const float*)d_in[8];
    const float* b2b  = (const float*)d_in[9];
    const float* Wlin = (const float*)d_in[10];
    const float* blin = (const float*)d_in[11];
    float* out = (float*)d_out;

    // ---- workspace carve-up (regions of 50000*256 bf16 = 25.6 MB) ----
    const size_t R = (size_t)N_NODES * HID;
    u16* R0 = (u16*)d_ws;          // xbf (first half) -> t2
    u16* R1 = R0 + R;              // partial-hist / zA (first half) + xf8 -> h1f8
    u16* R2 = R1 + R;              // t1 -> h2
    u16* R3 = R2 + R;              // h1 (live to end)
    u16* R4 = R3 + R;              // zB
    u16* xbf = R0;
    u16* zA  = R1;                                   // [50000,128] bf16
    int* partial = (int*)R1;                         // [128,6250] int (pre-gather_a)
    u8*  xf8 = (u8*)(R1 + (size_t)N_NODES * IN_CH);  // [50000,128] fp8 (2nd half)
    u8*  h1f8 = (u8*)R1;                             // [50000,256] fp8 (after zA dead)
    u16* t1  = R2;
    u16* h1  = R3;
    u16* zB  = R4;
    u16* t2  = R0;
    u16* h2  = R2;

    u16* wts = R4 + R;
    u16* W1aT = wts;                       // [256,128]
    u16* W2aT = W1aT + 256 * 128;          // [256,256]
    u16* W1bT = W2aT + 256 * 256;
    u16* W2bT = W1bT + 256 * 256;
    u16* WlinT = W2bT + 256 * 256;         // [128,512] (rows 40..127 zero)
    int* rowp   = (int*)(WlinT + 128 * 512);
    int* cursor = rowp + N_NODES;
    int* part   = cursor + N_NODES;
    u16* csr    = (u16*)(part + 64);       // [N_EDGES] u16 src ids

    dim3 blk(256);
    const int scanBlocks = (N_NODES + 1023) / 1024;  // 49
    const int aggBlocks  = (N_NODES + 3) / 4;        // 12500
    const int fillBlocks = 8 * ((N_EDGES + 2047) / 2048);
    dim3 g2(2, (N_NODES + 127) / 128);
    dim3 g1(1, (N_NODES + 127) / 128);

    // ---- prep: privatized histogram + conversions (fused) ----
    prep_fused<<<7530, blk, 0, stream>>>(ei, partial, x, xbf, xf8,
                                         W1a, W2a, W1b, W2b, Wlin,
                                         W1aT, W2aT, W1bT, W2bT, WlinT);
    scan1<<<scanBlocks, blk, 0, stream>>>(partial, rowp, part);
    scan3<<<(N_NODES + 255) / 256, blk, 0, stream>>>(rowp, part, cursor, scanBlocks);
    csr_fill<<<fillBlocks, blk, 0, stream>>>(ei, cursor, csr);

    // ---- Layer a ----
    gather_agg_f8_128<<<aggBlocks, blk, 0, stream>>>(xbf, xf8, rowp, cursor, csr, zA);
    gemm_mfma<<<g2, blk, 0, stream>>>(zA, nullptr, 0, IN_CH, W1aT, b1a,
                                      t1, nullptr, N_NODES, HID, IN_CH, 1, HID, 0);
    gemm_mfma<<<g2, blk, 0, stream>>>(t1, nullptr, 0, HID, W2aT, b2a,
                                      h1, h1f8, N_NODES, HID, HID, 1, HID, 0);

    // ---- Layer b ----
    gather_agg_f8_256<<<aggBlocks, blk, 0, stream>>>(h1, h1f8, rowp, cursor, csr, zB);
    gemm_mfma<<<g2, blk, 0, stream>>>(zB, nullptr, 0, HID, W1bT, b1b,
                                      t2, nullptr, N_NODES, HID, HID, 1, HID, 0);
    gemm_mfma<<<g2, blk, 0, stream>>>(t2, nullptr, 0, HID, W2bT, b2b,
                                      h2, nullptr, N_NODES, HID, HID, 1, HID, 0);

    // ---- Final linear on [h1 | h2] + fused log_softmax -> d_out ----
    gemm_mfma<<<g1, blk, 0, stream>>>(h1, h2, HID, HID, WlinT, blin,
                                      out, nullptr, N_NODES, OUT_CH, 2 * HID, 0, OUT_CH, 1);
}

// Round 10
// 373.755 us; speedup vs baseline: 1.0425x; 1.0425x over previous
//
#include <hip/hip_runtime.h>
#include <math.h>

// Problem constants
#define N_NODES 50000
#define N_EDGES 800000
#define IN_CH 128
#define HID 256
#define OUT_CH 40
#define GRP 6250          // nodes per dst-group (8 groups)
#define NCHUNK 32         // edge-chunks for histogram (8*32 = 256 blocks)

typedef unsigned short u16;
typedef unsigned char u8;
typedef __attribute__((ext_vector_type(8))) short bf16x8;
typedef __attribute__((ext_vector_type(4))) float f32x4;
typedef __attribute__((ext_vector_type(2))) float f32x2;

__device__ __forceinline__ float bf2f(u16 u) {
    union { unsigned int i; float f; } v; v.i = ((unsigned int)u) << 16; return v.f;
}
__device__ __forceinline__ u16 f2bf(float f) {   // round-to-nearest-even
    union { float f; unsigned int i; } v; v.f = f;
    unsigned int x = v.i;
    x += 0x7fffu + ((x >> 16) & 1u);
    return (u16)(x >> 16);
}

#define GLOBAL_AS __attribute__((address_space(1)))
#define LDS_AS __attribute__((address_space(3)))
__device__ __forceinline__ void async_cp16(const void* g, void* l) {
    __builtin_amdgcn_global_load_lds((const GLOBAL_AS unsigned int*)g,
                                     (LDS_AS unsigned int*)l, 16, 0, 0);
}

// ===========================================================================
// LDS-privatized degree histogram (own kernel so its 25 KB LDS doesn't
// throttle the streaming prep blocks — R9 lesson).
// 256 blocks = 8 dst-groups x 32 edge-chunks; non-atomic partial writes.
// ===========================================================================
__global__ __launch_bounds__(256) void hist_priv(
    const int* __restrict__ ei, int* __restrict__ partial)
{
    __shared__ int hist[GRP];     // 25 KB
    const int b = blockIdx.x;
    const int g = b & 7;          // dst-group
    const int sub = b >> 3;       // edge-chunk 0..31
    const int lo = g * GRP;
    const int CH = N_EDGES / NCHUNK;   // 25000
    for (int i = threadIdx.x; i < GRP; i += 256) hist[i] = 0;
    __syncthreads();
    const int* dsts = ei + N_EDGES + sub * CH;
    for (int k = threadIdx.x; k < CH; k += 256) {
        int r = dsts[k] - lo;
        if ((unsigned)r < (unsigned)GRP) atomicAdd(&hist[r], 1);
    }
    __syncthreads();
    int* po = partial + (size_t)b * GRP;
    for (int i = threadIdx.x; i < GRP; i += 256) po[i] = hist[i];
}

// ===========================================================================
// Fused prep (no LDS): x->{bf16,fp8} + 5 weight transposes.
// Block ranges: [0,6250) conv_x (1.6M float4 / 256); [6250,7402) transposes.
// ===========================================================================
__device__ __forceinline__ void tr_one(
    const float* __restrict__ in, u16* __restrict__ out, int K, int N, int n)
{
    for (int k = threadIdx.x; k < K; k += 256) {
        float v = (n < N) ? in[(size_t)k * N + n] : 0.f;
        out[(size_t)n * K + k] = f2bf(v);
    }
}

__global__ __launch_bounds__(256) void prep_fused(
    const float* __restrict__ x, u16* __restrict__ xb, u8* __restrict__ xf8,
    const float* __restrict__ W1a, const float* __restrict__ W2a,
    const float* __restrict__ W1b, const float* __restrict__ W2b,
    const float* __restrict__ Wlin,
    u16* __restrict__ W1aT, u16* __restrict__ W2aT,
    u16* __restrict__ W1bT, u16* __restrict__ W2bT, u16* __restrict__ WlinT)
{
    int b = blockIdx.x;
    if (b < 6250) {
        int i = b * 256 + threadIdx.x;
        float4 v = ((const float4*)x)[i];
        ushort4 o;
        o.x = f2bf(v.x); o.y = f2bf(v.y); o.z = f2bf(v.z); o.w = f2bf(v.w);
        ((ushort4*)xb)[i] = o;
        int p = __builtin_amdgcn_cvt_pk_fp8_f32(v.x, v.y, 0, false);
        p = __builtin_amdgcn_cvt_pk_fp8_f32(v.z, v.w, p, true);
        ((unsigned int*)xf8)[i] = (unsigned int)p;
    } else {
        int t = b - 6250;
        if (t < 256)       tr_one(W1a, W1aT, IN_CH, HID, t);
        else if (t < 512)  tr_one(W2a, W2aT, HID, HID, t - 256);
        else if (t < 768)  tr_one(W1b, W1bT, HID, HID, t - 512);
        else if (t < 1024) tr_one(W2b, W2bT, HID, HID, t - 768);
        else               tr_one(Wlin, WlinT, 2 * HID, OUT_CH, t - 1024);
    }
}

// ===========================================================================
// scan1: per-node degree = sum of 32 partials; block-scan 1024 nodes.
// ===========================================================================
__global__ __launch_bounds__(256) void scan1(
    const int* __restrict__ partial, int* __restrict__ excl,
    int* __restrict__ partials_out)
{
    __shared__ int lds[256];
    const int tid = threadIdx.x;
    const int base = blockIdx.x * 1024 + tid * 4;
    int v[4]; int s = 0;
#pragma unroll
    for (int i = 0; i < 4; i++) {
        int idx = base + i;
        int d = 0;
        if (idx < N_NODES) {
            int g = idx / GRP;
            int off = idx - g * GRP;
#pragma unroll
            for (int sub = 0; sub < NCHUNK; sub++)
                d += partial[(size_t)(sub * 8 + g) * GRP + off];
        }
        v[i] = d;
        s += d;
    }
    lds[tid] = s;
    __syncthreads();
    for (int off = 1; off < 256; off <<= 1) {
        int t = (tid >= off) ? lds[tid - off] : 0;
        __syncthreads();
        lds[tid] += t;
        __syncthreads();
    }
    int run = lds[tid] - s;
#pragma unroll
    for (int i = 0; i < 4; i++) {
        int idx = base + i;
        if (idx < N_NODES) excl[idx] = run;
        run += v[i];
    }
    if (tid == 255) partials_out[blockIdx.x] = lds[255];
}

// scan3: each block wave-scans the 49 block partials itself, adds offsets.
__global__ __launch_bounds__(256) void scan3(
    int* __restrict__ excl, const int* __restrict__ partials,
    int* __restrict__ cursor, int nPart)
{
    __shared__ int bp[64];
    const int tid = threadIdx.x;
    if (tid < 64) {
        int orig = (tid < nPart) ? partials[tid] : 0;
        int v = orig;
#pragma unroll
        for (int off = 1; off < 64; off <<= 1) {
            int t = __shfl_up(v, off, 64);
            if (tid >= off) v += t;
        }
        bp[tid] = v - orig;
    }
    __syncthreads();
    int idx = blockIdx.x * 256 + tid;
    if (idx < N_NODES) {
        int r = excl[idx] + bp[idx >> 10];
        excl[idx] = r;
        cursor[idx] = r;
    }
}

// Dst-sharded fill: group g = blockIdx&7 handles dst in [g*GRP,(g+1)*GRP).
__global__ __launch_bounds__(256) void csr_fill(
    const int* __restrict__ ei, int* __restrict__ cursor, u16* __restrict__ csr_src)
{
    const int g = blockIdx.x & 7;
    const int c = blockIdx.x >> 3;
    const int lo = g * GRP, hi = lo + GRP;
    const int base = c * 2048;
#pragma unroll
    for (int i = 0; i < 8; i++) {
        int e = base + i * 256 + threadIdx.x;
        if (e < N_EDGES) {
            int s = ei[e];
            int d = ei[N_EDGES + e];
            if (d >= lo && d < hi) {
                int pos = atomicAdd(&cursor[d], 1);
                csr_src[pos] = (u16)s;
            }
        }
    }
}

// ===========================================================================
// Gather aggregation, fp8 neighbor table + bf16 self term, fp32 accumulate:
//   out[n] = feat_bf[n] + sum_{e in row n} fp8(feat[src[e]])
// One 64-lane wave per node; 4-deep unroll for MLP.
// ===========================================================================
__global__ __launch_bounds__(256) void gather_agg_f8_128(
    const u16* __restrict__ feat_bf, const u8* __restrict__ feat_f8,
    const int* __restrict__ row_ptr, const int* __restrict__ row_end,
    const u16* __restrict__ csr_src, u16* __restrict__ out)
{
    int node = (blockIdx.x * 256 + threadIdx.x) >> 6;
    int lane = threadIdx.x & 63;
    if (node >= N_NODES) return;
    ushort2 sv = ((const ushort2*)(feat_bf + (size_t)node * IN_CH))[lane];
    float ax = bf2f(sv.x), ay = bf2f(sv.y);
    int j = row_ptr[node], e = row_end[node];
    for (; j + 4 <= e; j += 4) {
        int s0 = csr_src[j], s1 = csr_src[j + 1];
        int s2 = csr_src[j + 2], s3 = csr_src[j + 3];
        int v0 = ((const u16*)(feat_f8 + (size_t)s0 * IN_CH))[lane];
        int v1 = ((const u16*)(feat_f8 + (size_t)s1 * IN_CH))[lane];
        int v2 = ((const u16*)(feat_f8 + (size_t)s2 * IN_CH))[lane];
        int v3 = ((const u16*)(feat_f8 + (size_t)s3 * IN_CH))[lane];
        f32x2 d0 = __builtin_amdgcn_cvt_pk_f32_fp8(v0, false);
        f32x2 d1 = __builtin_amdgcn_cvt_pk_f32_fp8(v1, false);
        f32x2 d2 = __builtin_amdgcn_cvt_pk_f32_fp8(v2, false);
        f32x2 d3 = __builtin_amdgcn_cvt_pk_f32_fp8(v3, false);
        ax += (d0.x + d1.x) + (d2.x + d3.x);
        ay += (d0.y + d1.y) + (d2.y + d3.y);
    }
    for (; j < e; j++) {
        int sa = csr_src[j];
        int va = ((const u16*)(feat_f8 + (size_t)sa * IN_CH))[lane];
        f32x2 da = __builtin_amdgcn_cvt_pk_f32_fp8(va, false);
        ax += da.x; ay += da.y;
    }
    ushort2 o; o.x = f2bf(ax); o.y = f2bf(ay);
    ((ushort2*)(out + (size_t)node * IN_CH))[lane] = o;
}

__global__ __launch_bounds__(256) void gather_agg_f8_256(
    const u16* __restrict__ feat_bf, const u8* __restrict__ feat_f8,
    const int* __restrict__ row_ptr, const int* __restrict__ row_end,
    const u16* __restrict__ csr_src, u16* __restrict__ out)
{
    int node = (blockIdx.x * 256 + threadIdx.x) >> 6;
    int lane = threadIdx.x & 63;
    if (node >= N_NODES) return;
    ushort4 sv = ((const ushort4*)(feat_bf + (size_t)node * HID))[lane];
    float ax = bf2f(sv.x), ay = bf2f(sv.y), az = bf2f(sv.z), aw = bf2f(sv.w);
    int j = row_ptr[node], e = row_end[node];
    for (; j + 4 <= e; j += 4) {
        int s0 = csr_src[j], s1 = csr_src[j + 1];
        int s2 = csr_src[j + 2], s3 = csr_src[j + 3];
        int v0 = ((const int*)(feat_f8 + (size_t)s0 * HID))[lane];
        int v1 = ((const int*)(feat_f8 + (size_t)s1 * HID))[lane];
        int v2 = ((const int*)(feat_f8 + (size_t)s2 * HID))[lane];
        int v3 = ((const int*)(feat_f8 + (size_t)s3 * HID))[lane];
        f32x2 l0 = __builtin_amdgcn_cvt_pk_f32_fp8(v0, false);
        f32x2 h0 = __builtin_amdgcn_cvt_pk_f32_fp8(v0, true);
        f32x2 l1 = __builtin_amdgcn_cvt_pk_f32_fp8(v1, false);
        f32x2 h1v = __builtin_amdgcn_cvt_pk_f32_fp8(v1, true);
        f32x2 l2 = __builtin_amdgcn_cvt_pk_f32_fp8(v2, false);
        f32x2 h2v = __builtin_amdgcn_cvt_pk_f32_fp8(v2, true);
        f32x2 l3 = __builtin_amdgcn_cvt_pk_f32_fp8(v3, false);
        f32x2 h3 = __builtin_amdgcn_cvt_pk_f32_fp8(v3, true);
        ax += (l0.x + l1.x) + (l2.x + l3.x);
        ay += (l0.y + l1.y) + (l2.y + l3.y);
        az += (h0.x + h1v.x) + (h2v.x + h3.x);
        aw += (h0.y + h1v.y) + (h2v.y + h3.y);
    }
    for (; j < e; j++) {
        int sa = csr_src[j];
        int va = ((const int*)(feat_f8 + (size_t)sa * HID))[lane];
        f32x2 la = __builtin_amdgcn_cvt_pk_f32_fp8(va, false);
        f32x2 ha = __builtin_amdgcn_cvt_pk_f32_fp8(va, true);
        ax += la.x; ay += la.y; az += ha.x; aw += ha.y;
    }
    ushort4 o;
    o.x = f2bf(ax); o.y = f2bf(ay); o.z = f2bf(az); o.w = f2bf(aw);
    ((ushort4*)(out + (size_t)node * HID))[lane] = o;
}

// ===========================================================================
// bf16 MFMA GEMM (m97 structure, BK=32): out = act(Aeff[M,K] @ BT^T + bias)
// outF8 != null: additionally store e4m3 copy (fp8 neighbor table for gather).
// ===========================================================================
__global__ __launch_bounds__(256, 3) void gemm_mfma(
    const u16* __restrict__ A, const u16* __restrict__ Acat, int Ksplit, int ldA,
    const u16* __restrict__ BT, const float* __restrict__ bias,
    void* __restrict__ out, u8* __restrict__ outF8,
    int M, int Nreal, int K, int relu, int ldOut, int fuseLS)
{
    __shared__ u16 As[128 * 32];
    __shared__ u16 Bs[128 * 32];

    const int tid = threadIdx.x;
    const int lane = tid & 63;
    const int wid = tid >> 6;
    const int wm = wid >> 1, wn = wid & 1;
    const int row0 = blockIdx.y * 128;
    const int col0 = blockIdx.x * 128;

    f32x4 acc[4][4];
#pragma unroll
    for (int i = 0; i < 4; i++)
#pragma unroll
        for (int j = 0; j < 4; j++) acc[i][j] = (f32x4){0.f, 0.f, 0.f, 0.f};

    for (int kk = 0; kk < K; kk += 32) {
        const u16* Abase = (Acat != nullptr && kk >= Ksplit) ? Acat : A;
        const int kbase = (Acat != nullptr && kk >= Ksplit) ? (kk - Ksplit) : kk;
#pragma unroll
        for (int i = 0; i < 2; i++) {
            int chunk = i * 256 + tid;
            int r = chunk >> 2, c = chunk & 3;
            int grow = row0 + r; if (grow > M - 1) grow = M - 1;
            async_cp16(Abase + (size_t)grow * ldA + kbase + c * 8, As + chunk * 8);
        }
#pragma unroll
        for (int i = 0; i < 2; i++) {
            int chunk = i * 256 + tid;
            int r = chunk >> 2, c = chunk & 3;
            async_cp16(BT + (size_t)(col0 + r) * K + kk + c * 8, Bs + chunk * 8);
        }
        __syncthreads();

        const int koff = (lane >> 4) * 8;
        const int am = wm * 64 + (lane & 15);
        const int bn = wn * 64 + (lane & 15);
        bf16x8 af[4], bfr[4];
#pragma unroll
        for (int t = 0; t < 4; t++) {
            af[t]  = *(const bf16x8*)(As + (am + t * 16) * 32 + koff);
            bfr[t] = *(const bf16x8*)(Bs + (bn + t * 16) * 32 + koff);
        }
#pragma unroll
        for (int mt = 0; mt < 4; mt++)
#pragma unroll
            for (int nt = 0; nt < 4; nt++)
                acc[mt][nt] = __builtin_amdgcn_mfma_f32_16x16x32_bf16(
                    af[mt], bfr[nt], acc[mt][nt], 0, 0, 0);
        __syncthreads();
    }

    if (fuseLS) {
        if (wn != 0) return;
        const int quad = lane >> 4, li = lane & 15;
        float b0 = bias[li];
        float b1 = bias[16 + li];
        float b2 = (li < 8) ? bias[32 + li] : 0.f;
        float* o = (float*)out;
#pragma unroll
        for (int mt = 0; mt < 4; mt++) {
#pragma unroll
            for (int reg = 0; reg < 4; reg++) {
                int row = row0 + wm * 64 + mt * 16 + quad * 4 + reg;
                float v0 = acc[mt][0][reg] + b0;
                float v1 = acc[mt][1][reg] + b1;
                float v2 = (li < 8) ? (acc[mt][2][reg] + b2) : -INFINITY;
                float m = fmaxf(fmaxf(v0, v1), v2);
#pragma unroll
                for (int off = 1; off < 16; off <<= 1)
                    m = fmaxf(m, __shfl_xor(m, off, 64));
                float s = expf(v0 - m) + expf(v1 - m)
                        + ((li < 8) ? expf(v2 - m) : 0.f);
#pragma unroll
                for (int off = 1; off < 16; off <<= 1)
                    s += __shfl_xor(s, off, 64);
                float lg = m + logf(s);
                if (row < M) {
                    o[(size_t)row * OUT_CH + li] = v0 - lg;
                    o[(size_t)row * OUT_CH + 16 + li] = v1 - lg;
                    if (li < 8) o[(size_t)row * OUT_CH + 32 + li] = v2 - lg;
                }
            }
        }
        return;
    }

#pragma unroll
    for (int nt = 0; nt < 4; nt++) {
        int col = col0 + wn * 64 + nt * 16 + (lane & 15);
        bool colOk = (col < Nreal);
        float bv = colOk ? bias[col] : 0.f;
#pragma unroll
        for (int mt = 0; mt < 4; mt++) {
            int rbase = row0 + wm * 64 + mt * 16 + ((lane >> 4) << 2);
#pragma unroll
            for (int reg = 0; reg < 4; reg++) {
                int row = rbase + reg;
                if (colOk && row < M) {
                    float v = acc[mt][nt][reg] + bv;
                    if (relu) v = fmaxf(v, 0.f);
                    ((u16*)out)[(size_t)row * ldOut + col] = f2bf(v);
                    if (outF8 != nullptr) {
                        int pk = __builtin_amdgcn_cvt_pk_fp8_f32(v, v, 0, false);
                        outF8[(size_t)row * ldOut + col] = (u8)(pk & 0xff);
                    }
                }
            }
        }
    }
}

// ---------------------------------------------------------------------------
extern "C" void kernel_launch(void* const* d_in, const int* in_sizes, int n_in,
                              void* d_out, int out_size, void* d_ws, size_t ws_size,
                              hipStream_t stream)
{
    const float* x    = (const float*)d_in[0];
    const int*   ei   = (const int*)d_in[1];
    const float* W1a  = (const float*)d_in[2];
    const float* b1a  = (const float*)d_in[3];
    const float* W2a  = (const float*)d_in[4];
    const float* b2a  = (const float*)d_in[5];
    const float* W1b  = (const float*)d_in[6];
    const float* b1b  = (const float*)d_in[7];
    const float* W2b  = (const float*)d_in[8];
    const float* b2b  = (const float*)d_in[9];
    const float* Wlin = (const float*)d_in[10];
    const float* blin = (const float*)d_in[11];
    float* out = (float*)d_out;

    // ---- workspace carve-up (regions of 50000*256 bf16 = 25.6 MB) ----
    const size_t R = (size_t)N_NODES * HID;
    u16* R0 = (u16*)d_ws;          // xbf (first half) -> t2
    u16* R1 = R0 + R;              // partial-hist / zA (first half) + xf8 -> h1f8
    u16* R2 = R1 + R;              // t1 -> h2
    u16* R3 = R2 + R;              // h1 (live to end)
    u16* R4 = R3 + R;              // zB
    u16* xbf = R0;
    u16* zA  = R1;                                   // [50000,128] bf16
    int* partial = (int*)R1;                         // [256,6250] int = 6.4 MB (pre-gather_a)
    u8*  xf8 = (u8*)(R1 + (size_t)N_NODES * IN_CH);  // [50000,128] fp8 (2nd half)
    u8*  h1f8 = (u8*)R1;                             // [50000,256] fp8 (after zA dead)
    u16* t1  = R2;
    u16* h1  = R3;
    u16* zB  = R4;
    u16* t2  = R0;
    u16* h2  = R2;

    u16* wts = R4 + R;
    u16* W1aT = wts;                       // [256,128]
    u16* W2aT = W1aT + 256 * 128;          // [256,256]
    u16* W1bT = W2aT + 256 * 256;
    u16* W2bT = W1bT + 256 * 256;
    u16* WlinT = W2bT + 256 * 256;         // [128,512] (rows 40..127 zero)
    int* rowp   = (int*)(WlinT + 128 * 512);
    int* cursor = rowp + N_NODES;
    int* part   = cursor + N_NODES;
    u16* csr    = (u16*)(part + 64);       // [N_EDGES] u16 src ids

    dim3 blk(256);
    const int scanBlocks = (N_NODES + 1023) / 1024;  // 49
    const int aggBlocks  = (N_NODES + 3) / 4;        // 12500
    const int fillBlocks = 8 * ((N_EDGES + 2047) / 2048);
    dim3 g2(2, (N_NODES + 127) / 128);
    dim3 g1(1, (N_NODES + 127) / 128);

    // ---- prep: histogram (own kernel, 25 KB LDS) + streaming conversions ----
    hist_priv<<<8 * NCHUNK, blk, 0, stream>>>(ei, partial);
    prep_fused<<<7402, blk, 0, stream>>>(x, xbf, xf8,
                                         W1a, W2a, W1b, W2b, Wlin,
                                         W1aT, W2aT, W1bT, W2bT, WlinT);
    scan1<<<scanBlocks, blk, 0, stream>>>(partial, rowp, part);
    scan3<<<(N_NODES + 255) / 256, blk, 0, stream>>>(rowp, part, cursor, scanBlocks);
    csr_fill<<<fillBlocks, blk, 0, stream>>>(ei, cursor, csr);

    // ---- Layer a ----
    gather_agg_f8_128<<<aggBlocks, blk, 0, stream>>>(xbf, xf8, rowp, cursor, csr, zA);
    gemm_mfma<<<g2, blk, 0, stream>>>(zA, nullptr, 0, IN_CH, W1aT, b1a,
                                      t1, nullptr, N_NODES, HID, IN_CH, 1, HID, 0);
    gemm_mfma<<<g2, blk, 0, stream>>>(t1, nullptr, 0, HID, W2aT, b2a,
                                      h1, h1f8, N_NODES, HID, HID, 1, HID, 0);

    // ---- Layer b ----
    gather_agg_f8_256<<<aggBlocks, blk, 0, stream>>>(h1, h1f8, rowp, cursor, csr, zB);
    gemm_mfma<<<g2, blk, 0, stream>>>(zB, nullptr, 0, HID, W1bT, b1b,
                                      t2, nullptr, N_NODES, HID, HID, 1, HID, 0);
    gemm_mfma<<<g2, blk, 0, stream>>>(t2, nullptr, 0, HID, W2bT, b2b,
                                      h2, nullptr, N_NODES, HID, HID, 1, HID, 0);

    // ---- Final linear on [h1 | h2] + fused log_softmax -> d_out ----
    gemm_mfma<<<g1, blk, 0, stream>>>(h1, h2, HID, HID, WlinT, blin,
                                      out, nullptr, N_NODES, OUT_CH, 2 * HID, 0, OUT_CH, 1);
}

// Round 11
// 364.957 us; speedup vs baseline: 1.0676x; 1.0241x over previous
//
#include <hip/hip_runtime.h>
#include <math.h>

// Problem constants
#define N_NODES 50000
#define N_EDGES 800000
#define IN_CH 128
#define HID 256
#define OUT_CH 40
#define GRP 6250          // nodes per dst-group (8 groups)
#define NCHUNK 64         // edge-chunks for histogram (8*64 = 512 blocks)

typedef unsigned short u16;
typedef unsigned char u8;
typedef __attribute__((ext_vector_type(8))) short bf16x8;
typedef __attribute__((ext_vector_type(4))) float f32x4;
typedef __attribute__((ext_vector_type(2))) float f32x2;

__device__ __forceinline__ float bf2f(u16 u) {
    union { unsigned int i; float f; } v; v.i = ((unsigned int)u) << 16; return v.f;
}
__device__ __forceinline__ u16 f2bf(float f) {   // round-to-nearest-even
    union { float f; unsigned int i; } v; v.f = f;
    unsigned int x = v.i;
    x += 0x7fffu + ((x >> 16) & 1u);
    return (u16)(x >> 16);
}

#define GLOBAL_AS __attribute__((address_space(1)))
#define LDS_AS __attribute__((address_space(3)))
__device__ __forceinline__ void async_cp16(const void* g, void* l) {
    __builtin_amdgcn_global_load_lds((const GLOBAL_AS unsigned int*)g,
                                     (LDS_AS unsigned int*)l, 16, 0, 0);
}

// ===========================================================================
// LDS-privatized degree histogram (own kernel: its 25 KB LDS must not
// throttle streaming prep blocks — R9 lesson). 512 blocks = 8 dst-groups x
// 64 edge-chunks (2 blocks/CU); int4-vectorized dst stream (R10 lesson:
// 256 scalar-walking blocks were latency-bound at 440 GB/s).
// ===========================================================================
__global__ __launch_bounds__(256) void hist_priv(
    const int* __restrict__ ei, int* __restrict__ partial)
{
    __shared__ int hist[GRP];     // 25 KB
    const int b = blockIdx.x;
    const int g = b & 7;          // dst-group
    const int sub = b >> 3;       // edge-chunk 0..63
    const int lo = g * GRP;
    const int CH4 = (N_EDGES / NCHUNK) / 4;   // 3125 int4s per chunk
    for (int i = threadIdx.x; i < GRP; i += 256) hist[i] = 0;
    __syncthreads();
    const int4* dsts = (const int4*)(ei + N_EDGES + sub * (N_EDGES / NCHUNK));
    for (int k = threadIdx.x; k < CH4; k += 256) {
        int4 d = dsts[k];
        int r0 = d.x - lo, r1 = d.y - lo, r2 = d.z - lo, r3 = d.w - lo;
        if ((unsigned)r0 < (unsigned)GRP) atomicAdd(&hist[r0], 1);
        if ((unsigned)r1 < (unsigned)GRP) atomicAdd(&hist[r1], 1);
        if ((unsigned)r2 < (unsigned)GRP) atomicAdd(&hist[r2], 1);
        if ((unsigned)r3 < (unsigned)GRP) atomicAdd(&hist[r3], 1);
    }
    __syncthreads();
    int* po = partial + (size_t)b * GRP;
    for (int i = threadIdx.x; i < GRP; i += 256) po[i] = hist[i];
}

// ===========================================================================
// Fused prep (no LDS): x->{bf16,fp8} + 5 weight transposes.
// Block ranges: [0,6250) conv_x (1.6M float4 / 256); [6250,7402) transposes.
// ===========================================================================
__device__ __forceinline__ void tr_one(
    const float* __restrict__ in, u16* __restrict__ out, int K, int N, int n)
{
    for (int k = threadIdx.x; k < K; k += 256) {
        float v = (n < N) ? in[(size_t)k * N + n] : 0.f;
        out[(size_t)n * K + k] = f2bf(v);
    }
}

__global__ __launch_bounds__(256) void prep_fused(
    const float* __restrict__ x, u16* __restrict__ xb, u8* __restrict__ xf8,
    const float* __restrict__ W1a, const float* __restrict__ W2a,
    const float* __restrict__ W1b, const float* __restrict__ W2b,
    const float* __restrict__ Wlin,
    u16* __restrict__ W1aT, u16* __restrict__ W2aT,
    u16* __restrict__ W1bT, u16* __restrict__ W2bT, u16* __restrict__ WlinT)
{
    int b = blockIdx.x;
    if (b < 6250) {
        int i = b * 256 + threadIdx.x;
        float4 v = ((const float4*)x)[i];
        ushort4 o;
        o.x = f2bf(v.x); o.y = f2bf(v.y); o.z = f2bf(v.z); o.w = f2bf(v.w);
        ((ushort4*)xb)[i] = o;
        int p = __builtin_amdgcn_cvt_pk_fp8_f32(v.x, v.y, 0, false);
        p = __builtin_amdgcn_cvt_pk_fp8_f32(v.z, v.w, p, true);
        ((unsigned int*)xf8)[i] = (unsigned int)p;
    } else {
        int t = b - 6250;
        if (t < 256)       tr_one(W1a, W1aT, IN_CH, HID, t);
        else if (t < 512)  tr_one(W2a, W2aT, HID, HID, t - 256);
        else if (t < 768)  tr_one(W1b, W1bT, HID, HID, t - 512);
        else if (t < 1024) tr_one(W2b, W2bT, HID, HID, t - 768);
        else               tr_one(Wlin, WlinT, 2 * HID, OUT_CH, t - 1024);
    }
}

// ===========================================================================
// scan1: per-node degree = sum of 64 partials; block-scan 1024 nodes.
// ===========================================================================
__global__ __launch_bounds__(256) void scan1(
    const int* __restrict__ partial, int* __restrict__ excl,
    int* __restrict__ partials_out)
{
    __shared__ int lds[256];
    const int tid = threadIdx.x;
    const int base = blockIdx.x * 1024 + tid * 4;
    int v[4]; int s = 0;
#pragma unroll
    for (int i = 0; i < 4; i++) {
        int idx = base + i;
        int d = 0;
        if (idx < N_NODES) {
            int g = idx / GRP;
            int off = idx - g * GRP;
#pragma unroll
            for (int sub = 0; sub < NCHUNK; sub++)
                d += partial[(size_t)(sub * 8 + g) * GRP + off];
        }
        v[i] = d;
        s += d;
    }
    lds[tid] = s;
    __syncthreads();
    for (int off = 1; off < 256; off <<= 1) {
        int t = (tid >= off) ? lds[tid - off] : 0;
        __syncthreads();
        lds[tid] += t;
        __syncthreads();
    }
    int run = lds[tid] - s;
#pragma unroll
    for (int i = 0; i < 4; i++) {
        int idx = base + i;
        if (idx < N_NODES) excl[idx] = run;
        run += v[i];
    }
    if (tid == 255) partials_out[blockIdx.x] = lds[255];
}

// scan3: each block wave-scans the 49 block partials itself, adds offsets.
__global__ __launch_bounds__(256) void scan3(
    int* __restrict__ excl, const int* __restrict__ partials,
    int* __restrict__ cursor, int nPart)
{
    __shared__ int bp[64];
    const int tid = threadIdx.x;
    if (tid < 64) {
        int orig = (tid < nPart) ? partials[tid] : 0;
        int v = orig;
#pragma unroll
        for (int off = 1; off < 64; off <<= 1) {
            int t = __shfl_up(v, off, 64);
            if (tid >= off) v += t;
        }
        bp[tid] = v - orig;
    }
    __syncthreads();
    int idx = blockIdx.x * 256 + tid;
    if (idx < N_NODES) {
        int r = excl[idx] + bp[idx >> 10];
        excl[idx] = r;
        cursor[idx] = r;
    }
}

// Dst-sharded fill: group g = blockIdx&7 handles dst in [g*GRP,(g+1)*GRP).
__global__ __launch_bounds__(256) void csr_fill(
    const int* __restrict__ ei, int* __restrict__ cursor, u16* __restrict__ csr_src)
{
    const int g = blockIdx.x & 7;
    const int c = blockIdx.x >> 3;
    const int lo = g * GRP, hi = lo + GRP;
    const int base = c * 2048;
#pragma unroll
    for (int i = 0; i < 8; i++) {
        int e = base + i * 256 + threadIdx.x;
        if (e < N_EDGES) {
            int s = ei[e];
            int d = ei[N_EDGES + e];
            if (d >= lo && d < hi) {
                int pos = atomicAdd(&cursor[d], 1);
                csr_src[pos] = (u16)s;
            }
        }
    }
}

// ===========================================================================
// Gather aggregation, fp8 neighbor table + bf16 self term, fp32 accumulate:
//   out[n] = feat_bf[n] + sum_{e in row n} fp8(feat[src[e]])
// One 64-lane wave per node; 4-deep unroll for MLP.
// ===========================================================================
__global__ __launch_bounds__(256) void gather_agg_f8_128(
    const u16* __restrict__ feat_bf, const u8* __restrict__ feat_f8,
    const int* __restrict__ row_ptr, const int* __restrict__ row_end,
    const u16* __restrict__ csr_src, u16* __restrict__ out)
{
    int node = (blockIdx.x * 256 + threadIdx.x) >> 6;
    int lane = threadIdx.x & 63;
    if (node >= N_NODES) return;
    ushort2 sv = ((const ushort2*)(feat_bf + (size_t)node * IN_CH))[lane];
    float ax = bf2f(sv.x), ay = bf2f(sv.y);
    int j = row_ptr[node], e = row_end[node];
    for (; j + 4 <= e; j += 4) {
        int s0 = csr_src[j], s1 = csr_src[j + 1];
        int s2 = csr_src[j + 2], s3 = csr_src[j + 3];
        int v0 = ((const u16*)(feat_f8 + (size_t)s0 * IN_CH))[lane];
        int v1 = ((const u16*)(feat_f8 + (size_t)s1 * IN_CH))[lane];
        int v2 = ((const u16*)(feat_f8 + (size_t)s2 * IN_CH))[lane];
        int v3 = ((const u16*)(feat_f8 + (size_t)s3 * IN_CH))[lane];
        f32x2 d0 = __builtin_amdgcn_cvt_pk_f32_fp8(v0, false);
        f32x2 d1 = __builtin_amdgcn_cvt_pk_f32_fp8(v1, false);
        f32x2 d2 = __builtin_amdgcn_cvt_pk_f32_fp8(v2, false);
        f32x2 d3 = __builtin_amdgcn_cvt_pk_f32_fp8(v3, false);
        ax += (d0.x + d1.x) + (d2.x + d3.x);
        ay += (d0.y + d1.y) + (d2.y + d3.y);
    }
    for (; j < e; j++) {
        int sa = csr_src[j];
        int va = ((const u16*)(feat_f8 + (size_t)sa * IN_CH))[lane];
        f32x2 da = __builtin_amdgcn_cvt_pk_f32_fp8(va, false);
        ax += da.x; ay += da.y;
    }
    ushort2 o; o.x = f2bf(ax); o.y = f2bf(ay);
    ((ushort2*)(out + (size_t)node * IN_CH))[lane] = o;
}

__global__ __launch_bounds__(256) void gather_agg_f8_256(
    const u16* __restrict__ feat_bf, const u8* __restrict__ feat_f8,
    const int* __restrict__ row_ptr, const int* __restrict__ row_end,
    const u16* __restrict__ csr_src, u16* __restrict__ out)
{
    int node = (blockIdx.x * 256 + threadIdx.x) >> 6;
    int lane = threadIdx.x & 63;
    if (node >= N_NODES) return;
    ushort4 sv = ((const ushort4*)(feat_bf + (size_t)node * HID))[lane];
    float ax = bf2f(sv.x), ay = bf2f(sv.y), az = bf2f(sv.z), aw = bf2f(sv.w);
    int j = row_ptr[node], e = row_end[node];
    for (; j + 4 <= e; j += 4) {
        int s0 = csr_src[j], s1 = csr_src[j + 1];
        int s2 = csr_src[j + 2], s3 = csr_src[j + 3];
        int v0 = ((const int*)(feat_f8 + (size_t)s0 * HID))[lane];
        int v1 = ((const int*)(feat_f8 + (size_t)s1 * HID))[lane];
        int v2 = ((const int*)(feat_f8 + (size_t)s2 * HID))[lane];
        int v3 = ((const int*)(feat_f8 + (size_t)s3 * HID))[lane];
        f32x2 l0 = __builtin_amdgcn_cvt_pk_f32_fp8(v0, false);
        f32x2 h0 = __builtin_amdgcn_cvt_pk_f32_fp8(v0, true);
        f32x2 l1 = __builtin_amdgcn_cvt_pk_f32_fp8(v1, false);
        f32x2 h1v = __builtin_amdgcn_cvt_pk_f32_fp8(v1, true);
        f32x2 l2 = __builtin_amdgcn_cvt_pk_f32_fp8(v2, false);
        f32x2 h2v = __builtin_amdgcn_cvt_pk_f32_fp8(v2, true);
        f32x2 l3 = __builtin_amdgcn_cvt_pk_f32_fp8(v3, false);
        f32x2 h3 = __builtin_amdgcn_cvt_pk_f32_fp8(v3, true);
        ax += (l0.x + l1.x) + (l2.x + l3.x);
        ay += (l0.y + l1.y) + (l2.y + l3.y);
        az += (h0.x + h1v.x) + (h2v.x + h3.x);
        aw += (h0.y + h1v.y) + (h2v.y + h3.y);
    }
    for (; j < e; j++) {
        int sa = csr_src[j];
        int va = ((const int*)(feat_f8 + (size_t)sa * HID))[lane];
        f32x2 la = __builtin_amdgcn_cvt_pk_f32_fp8(va, false);
        f32x2 ha = __builtin_amdgcn_cvt_pk_f32_fp8(va, true);
        ax += la.x; ay += la.y; az += ha.x; aw += ha.y;
    }
    ushort4 o;
    o.x = f2bf(ax); o.y = f2bf(ay); o.z = f2bf(az); o.w = f2bf(aw);
    ((ushort4*)(out + (size_t)node * HID))[lane] = o;
}

// ===========================================================================
// bf16 MFMA GEMM (m97 structure, BK=32): out = act(Aeff[M,K] @ BT^T + bias)
// outF8 != null: additionally store e4m3 copy (fp8 neighbor table for gather).
// ===========================================================================
__global__ __launch_bounds__(256, 3) void gemm_mfma(
    const u16* __restrict__ A, const u16* __restrict__ Acat, int Ksplit, int ldA,
    const u16* __restrict__ BT, const float* __restrict__ bias,
    void* __restrict__ out, u8* __restrict__ outF8,
    int M, int Nreal, int K, int relu, int ldOut, int fuseLS)
{
    __shared__ u16 As[128 * 32];
    __shared__ u16 Bs[128 * 32];

    const int tid = threadIdx.x;
    const int lane = tid & 63;
    const int wid = tid >> 6;
    const int wm = wid >> 1, wn = wid & 1;
    const int row0 = blockIdx.y * 128;
    const int col0 = blockIdx.x * 128;

    f32x4 acc[4][4];
#pragma unroll
    for (int i = 0; i < 4; i++)
#pragma unroll
        for (int j = 0; j < 4; j++) acc[i][j] = (f32x4){0.f, 0.f, 0.f, 0.f};

    for (int kk = 0; kk < K; kk += 32) {
        const u16* Abase = (Acat != nullptr && kk >= Ksplit) ? Acat : A;
        const int kbase = (Acat != nullptr && kk >= Ksplit) ? (kk - Ksplit) : kk;
#pragma unroll
        for (int i = 0; i < 2; i++) {
            int chunk = i * 256 + tid;
            int r = chunk >> 2, c = chunk & 3;
            int grow = row0 + r; if (grow > M - 1) grow = M - 1;
            async_cp16(Abase + (size_t)grow * ldA + kbase + c * 8, As + chunk * 8);
        }
#pragma unroll
        for (int i = 0; i < 2; i++) {
            int chunk = i * 256 + tid;
            int r = chunk >> 2, c = chunk & 3;
            async_cp16(BT + (size_t)(col0 + r) * K + kk + c * 8, Bs + chunk * 8);
        }
        __syncthreads();

        const int koff = (lane >> 4) * 8;
        const int am = wm * 64 + (lane & 15);
        const int bn = wn * 64 + (lane & 15);
        bf16x8 af[4], bfr[4];
#pragma unroll
        for (int t = 0; t < 4; t++) {
            af[t]  = *(const bf16x8*)(As + (am + t * 16) * 32 + koff);
            bfr[t] = *(const bf16x8*)(Bs + (bn + t * 16) * 32 + koff);
        }
#pragma unroll
        for (int mt = 0; mt < 4; mt++)
#pragma unroll
            for (int nt = 0; nt < 4; nt++)
                acc[mt][nt] = __builtin_amdgcn_mfma_f32_16x16x32_bf16(
                    af[mt], bfr[nt], acc[mt][nt], 0, 0, 0);
        __syncthreads();
    }

    if (fuseLS) {
        if (wn != 0) return;
        const int quad = lane >> 4, li = lane & 15;
        float b0 = bias[li];
        float b1 = bias[16 + li];
        float b2 = (li < 8) ? bias[32 + li] : 0.f;
        float* o = (float*)out;
#pragma unroll
        for (int mt = 0; mt < 4; mt++) {
#pragma unroll
            for (int reg = 0; reg < 4; reg++) {
                int row = row0 + wm * 64 + mt * 16 + quad * 4 + reg;
                float v0 = acc[mt][0][reg] + b0;
                float v1 = acc[mt][1][reg] + b1;
                float v2 = (li < 8) ? (acc[mt][2][reg] + b2) : -INFINITY;
                float m = fmaxf(fmaxf(v0, v1), v2);
#pragma unroll
                for (int off = 1; off < 16; off <<= 1)
                    m = fmaxf(m, __shfl_xor(m, off, 64));
                float s = expf(v0 - m) + expf(v1 - m)
                        + ((li < 8) ? expf(v2 - m) : 0.f);
#pragma unroll
                for (int off = 1; off < 16; off <<= 1)
                    s += __shfl_xor(s, off, 64);
                float lg = m + logf(s);
                if (row < M) {
                    o[(size_t)row * OUT_CH + li] = v0 - lg;
                    o[(size_t)row * OUT_CH + 16 + li] = v1 - lg;
                    if (li < 8) o[(size_t)row * OUT_CH + 32 + li] = v2 - lg;
                }
            }
        }
        return;
    }

#pragma unroll
    for (int nt = 0; nt < 4; nt++) {
        int col = col0 + wn * 64 + nt * 16 + (lane & 15);
        bool colOk = (col < Nreal);
        float bv = colOk ? bias[col] : 0.f;
#pragma unroll
        for (int mt = 0; mt < 4; mt++) {
            int rbase = row0 + wm * 64 + mt * 16 + ((lane >> 4) << 2);
#pragma unroll
            for (int reg = 0; reg < 4; reg++) {
                int row = rbase + reg;
                if (colOk && row < M) {
                    float v = acc[mt][nt][reg] + bv;
                    if (relu) v = fmaxf(v, 0.f);
                    ((u16*)out)[(size_t)row * ldOut + col] = f2bf(v);
                    if (outF8 != nullptr) {
                        int pk = __builtin_amdgcn_cvt_pk_fp8_f32(v, v, 0, false);
                        outF8[(size_t)row * ldOut + col] = (u8)(pk & 0xff);
                    }
                }
            }
        }
    }
}

// ---------------------------------------------------------------------------
extern "C" void kernel_launch(void* const* d_in, const int* in_sizes, int n_in,
                              void* d_out, int out_size, void* d_ws, size_t ws_size,
                              hipStream_t stream)
{
    const float* x    = (const float*)d_in[0];
    const int*   ei   = (const int*)d_in[1];
    const float* W1a  = (const float*)d_in[2];
    const float* b1a  = (const float*)d_in[3];
    const float* W2a  = (const float*)d_in[4];
    const float* b2a  = (const float*)d_in[5];
    const float* W1b  = (const float*)d_in[6];
    const float* b1b  = (const float*)d_in[7];
    const float* W2b  = (const float*)d_in[8];
    const float* b2b  = (const float*)d_in[9];
    const float* Wlin = (const float*)d_in[10];
    const float* blin = (const float*)d_in[11];
    float* out = (float*)d_out;

    // ---- workspace carve-up (regions of 50000*256 bf16 = 25.6 MB) ----
    const size_t R = (size_t)N_NODES * HID;
    u16* R0 = (u16*)d_ws;          // xbf (first half) -> t2
    u16* R1 = R0 + R;              // partial-hist / zA (first half) + xf8 -> h1f8
    u16* R2 = R1 + R;              // t1 -> h2
    u16* R3 = R2 + R;              // h1 (live to end)
    u16* R4 = R3 + R;              // zB
    u16* xbf = R0;
    u16* zA  = R1;                                   // [50000,128] bf16
    int* partial = (int*)R1;                         // [512,6250] int = 12.8 MB (pre-gather_a)
    u8*  xf8 = (u8*)(R1 + (size_t)N_NODES * IN_CH);  // [50000,128] fp8 (2nd half)
    u8*  h1f8 = (u8*)R1;                             // [50000,256] fp8 (after zA dead)
    u16* t1  = R2;
    u16* h1  = R3;
    u16* zB  = R4;
    u16* t2  = R0;
    u16* h2  = R2;

    u16* wts = R4 + R;
    u16* W1aT = wts;                       // [256,128]
    u16* W2aT = W1aT + 256 * 128;          // [256,256]
    u16* W1bT = W2aT + 256 * 256;
    u16* W2bT = W1bT + 256 * 256;
    u16* WlinT = W2bT + 256 * 256;         // [128,512] (rows 40..127 zero)
    int* rowp   = (int*)(WlinT + 128 * 512);
    int* cursor = rowp + N_NODES;
    int* part   = cursor + N_NODES;
    u16* csr    = (u16*)(part + 64);       // [N_EDGES] u16 src ids

    dim3 blk(256);
    const int scanBlocks = (N_NODES + 1023) / 1024;  // 49
    const int aggBlocks  = (N_NODES + 3) / 4;        // 12500
    const int fillBlocks = 8 * ((N_EDGES + 2047) / 2048);
    dim3 g2(2, (N_NODES + 127) / 128);
    dim3 g1(1, (N_NODES + 127) / 128);

    // ---- prep: histogram (own kernel, 25 KB LDS) + streaming conversions ----
    hist_priv<<<8 * NCHUNK, blk, 0, stream>>>(ei, partial);
    prep_fused<<<7402, blk, 0, stream>>>(x, xbf, xf8,
                                         W1a, W2a, W1b, W2b, Wlin,
                                         W1aT, W2aT, W1bT, W2bT, WlinT);
    scan1<<<scanBlocks, blk, 0, stream>>>(partial, rowp, part);
    scan3<<<(N_NODES + 255) / 256, blk, 0, stream>>>(rowp, part, cursor, scanBlocks);
    csr_fill<<<fillBlocks, blk, 0, stream>>>(ei, cursor, csr);

    // ---- Layer a ----
    gather_agg_f8_128<<<aggBlocks, blk, 0, stream>>>(xbf, xf8, rowp, cursor, csr, zA);
    gemm_mfma<<<g2, blk, 0, stream>>>(zA, nullptr, 0, IN_CH, W1aT, b1a,
                                      t1, nullptr, N_NODES, HID, IN_CH, 1, HID, 0);
    gemm_mfma<<<g2, blk, 0, stream>>>(t1, nullptr, 0, HID, W2aT, b2a,
                                      h1, h1f8, N_NODES, HID, HID, 1, HID, 0);

    // ---- Layer b ----
    gather_agg_f8_256<<<aggBlocks, blk, 0, stream>>>(h1, h1f8, rowp, cursor, csr, zB);
    gemm_mfma<<<g2, blk, 0, stream>>>(zB, nullptr, 0, HID, W1bT, b1b,
                                      t2, nullptr, N_NODES, HID, HID, 1, HID, 0);
    gemm_mfma<<<g2, blk, 0, stream>>>(t2, nullptr, 0, HID, W2bT, b2b,
                                      h2, nullptr, N_NODES, HID, HID, 1, HID, 0);

    // ---- Final linear on [h1 | h2] + fused log_softmax -> d_out ----
    gemm_mfma<<<g1, blk, 0, stream>>>(h1, h2, HID, HID, WlinT, blin,
                                      out, nullptr, N_NODES, OUT_CH, 2 * HID, 0, OUT_CH, 1);
}

// Round 12
// 352.138 us; speedup vs baseline: 1.1064x; 1.0364x over previous
//
#include <hip/hip_runtime.h>
#include <math.h>

// Problem constants
#define N_NODES 50000
#define N_EDGES 800000
#define IN_CH 128
#define HID 256
#define OUT_CH 40
#define GRP 6250          // nodes per dst-group (8 groups)
#define NCHUNK 64         // edge-chunks for histogram (8*64 = 512 blocks)

typedef unsigned short u16;
typedef unsigned char u8;
typedef __attribute__((ext_vector_type(8))) short bf16x8;
typedef __attribute__((ext_vector_type(4))) float f32x4;
typedef __attribute__((ext_vector_type(2))) float f32x2;

__device__ __forceinline__ float bf2f(u16 u) {
    union { unsigned int i; float f; } v; v.i = ((unsigned int)u) << 16; return v.f;
}
__device__ __forceinline__ u16 f2bf(float f) {   // round-to-nearest-even
    union { float f; unsigned int i; } v; v.f = f;
    unsigned int x = v.i;
    x += 0x7fffu + ((x >> 16) & 1u);
    return (u16)(x >> 16);
}

#define GLOBAL_AS __attribute__((address_space(1)))
#define LDS_AS __attribute__((address_space(3)))
__device__ __forceinline__ void async_cp16(const void* g, void* l) {
    __builtin_amdgcn_global_load_lds((const GLOBAL_AS unsigned int*)g,
                                     (LDS_AS unsigned int*)l, 16, 0, 0);
}

// ===========================================================================
// Fused prep (no LDS): x->{bf16,fp8} + weight transposes + u16 edge copies.
// Block ranges: [0,6250) conv_x; [6250,7813) edge-compress (400k int4);
//               [7813,8965) transposes.
// Runs FIRST: hist/csr_fill consume dst16/src16.
// ===========================================================================
__device__ __forceinline__ void tr_one(
    const float* __restrict__ in, u16* __restrict__ out, int K, int N, int n)
{
    for (int k = threadIdx.x; k < K; k += 256) {
        float v = (n < N) ? in[(size_t)k * N + n] : 0.f;
        out[(size_t)n * K + k] = f2bf(v);
    }
}

__global__ __launch_bounds__(256) void prep_fused(
    const float* __restrict__ x, u16* __restrict__ xb, u8* __restrict__ xf8,
    const int* __restrict__ ei, u16* __restrict__ e16,
    const float* __restrict__ W1a, const float* __restrict__ W2a,
    const float* __restrict__ W1b, const float* __restrict__ W2b,
    const float* __restrict__ Wlin,
    u16* __restrict__ W1aT, u16* __restrict__ W2aT,
    u16* __restrict__ W1bT, u16* __restrict__ W2bT, u16* __restrict__ WlinT)
{
    int b = blockIdx.x;
    if (b < 6250) {
        int i = b * 256 + threadIdx.x;
        float4 v = ((const float4*)x)[i];
        ushort4 o;
        o.x = f2bf(v.x); o.y = f2bf(v.y); o.z = f2bf(v.z); o.w = f2bf(v.w);
        ((ushort4*)xb)[i] = o;
        int p = __builtin_amdgcn_cvt_pk_fp8_f32(v.x, v.y, 0, false);
        p = __builtin_amdgcn_cvt_pk_fp8_f32(v.z, v.w, p, true);
        ((unsigned int*)xf8)[i] = (unsigned int)p;
    } else if (b < 7813) {
        int i = (b - 6250) * 256 + threadIdx.x;   // int4 index over 2*N_EDGES ints
        if (i < (2 * N_EDGES) / 4) {
            int4 v = ((const int4*)ei)[i];
            ushort4 o;
            o.x = (u16)v.x; o.y = (u16)v.y; o.z = (u16)v.z; o.w = (u16)v.w;
            ((ushort4*)e16)[i] = o;
        }
    } else {
        int t = b - 7813;
        if (t < 256)       tr_one(W1a, W1aT, IN_CH, HID, t);
        else if (t < 512)  tr_one(W2a, W2aT, HID, HID, t - 256);
        else if (t < 768)  tr_one(W1b, W1bT, HID, HID, t - 512);
        else if (t < 1024) tr_one(W2b, W2bT, HID, HID, t - 768);
        else               tr_one(Wlin, WlinT, 2 * HID, OUT_CH, t - 1024);
    }
}

// ===========================================================================
// LDS-privatized degree histogram, u16 dst stream + u16 partial output.
// 512 blocks = 8 dst-groups x 64 edge-chunks; per-chunk count <= 12500 < 64k.
// ===========================================================================
__global__ __launch_bounds__(256) void hist_priv(
    const u16* __restrict__ dst16, u16* __restrict__ partial)
{
    __shared__ int hist[GRP];     // 25 KB
    const int b = blockIdx.x;
    const int g = b & 7;          // dst-group
    const int sub = b >> 3;       // edge-chunk 0..63
    const int lo = g * GRP;
    const int CH = N_EDGES / NCHUNK;          // 12500
    for (int i = threadIdx.x; i < GRP; i += 256) hist[i] = 0;
    __syncthreads();
    const ushort4* dsts = (const ushort4*)(dst16 + sub * CH);
    for (int k = threadIdx.x; k < CH / 4; k += 256) {
        ushort4 d = dsts[k];
        int r0 = (int)d.x - lo, r1 = (int)d.y - lo;
        int r2 = (int)d.z - lo, r3 = (int)d.w - lo;
        if ((unsigned)r0 < (unsigned)GRP) atomicAdd(&hist[r0], 1);
        if ((unsigned)r1 < (unsigned)GRP) atomicAdd(&hist[r1], 1);
        if ((unsigned)r2 < (unsigned)GRP) atomicAdd(&hist[r2], 1);
        if ((unsigned)r3 < (unsigned)GRP) atomicAdd(&hist[r3], 1);
    }
    __syncthreads();
    u16* po = partial + (size_t)b * GRP;
    for (int i = threadIdx.x; i < GRP; i += 256) po[i] = (u16)hist[i];
}

// ===========================================================================
// scan1: per-node degree = sum of 64 u16 partials; block-scan 1024 nodes.
// ===========================================================================
__global__ __launch_bounds__(256) void scan1(
    const u16* __restrict__ partial, int* __restrict__ excl,
    int* __restrict__ partials_out)
{
    __shared__ int lds[256];
    const int tid = threadIdx.x;
    const int base = blockIdx.x * 1024 + tid * 4;
    int v[4]; int s = 0;
#pragma unroll
    for (int i = 0; i < 4; i++) {
        int idx = base + i;
        int d = 0;
        if (idx < N_NODES) {
            int g = idx / GRP;
            int off = idx - g * GRP;
#pragma unroll
            for (int sub = 0; sub < NCHUNK; sub++)
                d += partial[(size_t)(sub * 8 + g) * GRP + off];
        }
        v[i] = d;
        s += d;
    }
    lds[tid] = s;
    __syncthreads();
    for (int off = 1; off < 256; off <<= 1) {
        int t = (tid >= off) ? lds[tid - off] : 0;
        __syncthreads();
        lds[tid] += t;
        __syncthreads();
    }
    int run = lds[tid] - s;
#pragma unroll
    for (int i = 0; i < 4; i++) {
        int idx = base + i;
        if (idx < N_NODES) excl[idx] = run;
        run += v[i];
    }
    if (tid == 255) partials_out[blockIdx.x] = lds[255];
}

// scan3: each block wave-scans the 49 block partials itself, adds offsets.
__global__ __launch_bounds__(256) void scan3(
    int* __restrict__ excl, const int* __restrict__ partials,
    int* __restrict__ cursor, int nPart)
{
    __shared__ int bp[64];
    const int tid = threadIdx.x;
    if (tid < 64) {
        int orig = (tid < nPart) ? partials[tid] : 0;
        int v = orig;
#pragma unroll
        for (int off = 1; off < 64; off <<= 1) {
            int t = __shfl_up(v, off, 64);
            if (tid >= off) v += t;
        }
        bp[tid] = v - orig;
    }
    __syncthreads();
    int idx = blockIdx.x * 256 + tid;
    if (idx < N_NODES) {
        int r = excl[idx] + bp[idx >> 10];
        excl[idx] = r;
        cursor[idx] = r;
    }
}

// Dst-sharded fill on u16 edge copies: group g = blockIdx&7 owns
// dst in [g*GRP,(g+1)*GRP); 8x re-stream is now u16 (26 MB vs 51 MB).
__global__ __launch_bounds__(256) void csr_fill(
    const u16* __restrict__ src16, const u16* __restrict__ dst16,
    int* __restrict__ cursor, u16* __restrict__ csr_src)
{
    const int g = blockIdx.x & 7;
    const int c = blockIdx.x >> 3;
    const int lo = g * GRP, hi = lo + GRP;
    const int base = c * 2048;
#pragma unroll
    for (int i = 0; i < 8; i++) {
        int e = base + i * 256 + threadIdx.x;
        if (e < N_EDGES) {
            int d = dst16[e];
            if (d >= lo && d < hi) {
                int pos = atomicAdd(&cursor[d], 1);
                csr_src[pos] = src16[e];
            }
        }
    }
}

// ===========================================================================
// Gather aggregation, fp8 neighbor table + bf16 self term, fp32 accumulate:
//   out[n] = feat_bf[n] + sum_{e in row n} fp8(feat[src[e]])
// One 64-lane wave per node; 4-deep unroll for MLP.
// ===========================================================================
__global__ __launch_bounds__(256) void gather_agg_f8_128(
    const u16* __restrict__ feat_bf, const u8* __restrict__ feat_f8,
    const int* __restrict__ row_ptr, const int* __restrict__ row_end,
    const u16* __restrict__ csr_src, u16* __restrict__ out)
{
    int node = (blockIdx.x * 256 + threadIdx.x) >> 6;
    int lane = threadIdx.x & 63;
    if (node >= N_NODES) return;
    ushort2 sv = ((const ushort2*)(feat_bf + (size_t)node * IN_CH))[lane];
    float ax = bf2f(sv.x), ay = bf2f(sv.y);
    int j = row_ptr[node], e = row_end[node];
    for (; j + 4 <= e; j += 4) {
        int s0 = csr_src[j], s1 = csr_src[j + 1];
        int s2 = csr_src[j + 2], s3 = csr_src[j + 3];
        int v0 = ((const u16*)(feat_f8 + (size_t)s0 * IN_CH))[lane];
        int v1 = ((const u16*)(feat_f8 + (size_t)s1 * IN_CH))[lane];
        int v2 = ((const u16*)(feat_f8 + (size_t)s2 * IN_CH))[lane];
        int v3 = ((const u16*)(feat_f8 + (size_t)s3 * IN_CH))[lane];
        f32x2 d0 = __builtin_amdgcn_cvt_pk_f32_fp8(v0, false);
        f32x2 d1 = __builtin_amdgcn_cvt_pk_f32_fp8(v1, false);
        f32x2 d2 = __builtin_amdgcn_cvt_pk_f32_fp8(v2, false);
        f32x2 d3 = __builtin_amdgcn_cvt_pk_f32_fp8(v3, false);
        ax += (d0.x + d1.x) + (d2.x + d3.x);
        ay += (d0.y + d1.y) + (d2.y + d3.y);
    }
    for (; j < e; j++) {
        int sa = csr_src[j];
        int va = ((const u16*)(feat_f8 + (size_t)sa * IN_CH))[lane];
        f32x2 da = __builtin_amdgcn_cvt_pk_f32_fp8(va, false);
        ax += da.x; ay += da.y;
    }
    ushort2 o; o.x = f2bf(ax); o.y = f2bf(ay);
    ((ushort2*)(out + (size_t)node * IN_CH))[lane] = o;
}

__global__ __launch_bounds__(256) void gather_agg_f8_256(
    const u16* __restrict__ feat_bf, const u8* __restrict__ feat_f8,
    const int* __restrict__ row_ptr, const int* __restrict__ row_end,
    const u16* __restrict__ csr_src, u16* __restrict__ out)
{
    int node = (blockIdx.x * 256 + threadIdx.x) >> 6;
    int lane = threadIdx.x & 63;
    if (node >= N_NODES) return;
    ushort4 sv = ((const ushort4*)(feat_bf + (size_t)node * HID))[lane];
    float ax = bf2f(sv.x), ay = bf2f(sv.y), az = bf2f(sv.z), aw = bf2f(sv.w);
    int j = row_ptr[node], e = row_end[node];
    for (; j + 4 <= e; j += 4) {
        int s0 = csr_src[j], s1 = csr_src[j + 1];
        int s2 = csr_src[j + 2], s3 = csr_src[j + 3];
        int v0 = ((const int*)(feat_f8 + (size_t)s0 * HID))[lane];
        int v1 = ((const int*)(feat_f8 + (size_t)s1 * HID))[lane];
        int v2 = ((const int*)(feat_f8 + (size_t)s2 * HID))[lane];
        int v3 = ((const int*)(feat_f8 + (size_t)s3 * HID))[lane];
        f32x2 l0 = __builtin_amdgcn_cvt_pk_f32_fp8(v0, false);
        f32x2 h0 = __builtin_amdgcn_cvt_pk_f32_fp8(v0, true);
        f32x2 l1 = __builtin_amdgcn_cvt_pk_f32_fp8(v1, false);
        f32x2 h1v = __builtin_amdgcn_cvt_pk_f32_fp8(v1, true);
        f32x2 l2 = __builtin_amdgcn_cvt_pk_f32_fp8(v2, false);
        f32x2 h2v = __builtin_amdgcn_cvt_pk_f32_fp8(v2, true);
        f32x2 l3 = __builtin_amdgcn_cvt_pk_f32_fp8(v3, false);
        f32x2 h3 = __builtin_amdgcn_cvt_pk_f32_fp8(v3, true);
        ax += (l0.x + l1.x) + (l2.x + l3.x);
        ay += (l0.y + l1.y) + (l2.y + l3.y);
        az += (h0.x + h1v.x) + (h2v.x + h3.x);
        aw += (h0.y + h1v.y) + (h2v.y + h3.y);
    }
    for (; j < e; j++) {
        int sa = csr_src[j];
        int va = ((const int*)(feat_f8 + (size_t)sa * HID))[lane];
        f32x2 la = __builtin_amdgcn_cvt_pk_f32_fp8(va, false);
        f32x2 ha = __builtin_amdgcn_cvt_pk_f32_fp8(va, true);
        ax += la.x; ay += la.y; az += ha.x; aw += ha.y;
    }
    ushort4 o;
    o.x = f2bf(ax); o.y = f2bf(ay); o.z = f2bf(az); o.w = f2bf(aw);
    ((ushort4*)(out + (size_t)node * HID))[lane] = o;
}

// ===========================================================================
// Full-width bf16 MFMA GEMM: BM=128 x BN=256, 512 threads (8 waves of 64x64).
// One col-block per row-tile -> A streamed ONCE (grid (2,..) read it twice).
// out = act(A[M,K] @ BT^T + bias); BT = [256,K]. outF8: extra e4m3 store.
// ===========================================================================
__global__ __launch_bounds__(512, 4) void gemm_wide(
    const u16* __restrict__ A, int ldA,
    const u16* __restrict__ BT, const float* __restrict__ bias,
    u16* __restrict__ out, u8* __restrict__ outF8,
    int M, int K, int ldOut)
{
    __shared__ u16 As[128 * 32];   // 8 KB
    __shared__ u16 Bs[256 * 32];   // 16 KB

    const int tid = threadIdx.x;
    const int lane = tid & 63;
    const int wid = tid >> 6;          // 0..7
    const int wm = wid >> 2, wn = wid & 3;
    const int row0 = blockIdx.x * 128;

    f32x4 acc[4][4];
#pragma unroll
    for (int i = 0; i < 4; i++)
#pragma unroll
        for (int j = 0; j < 4; j++) acc[i][j] = (f32x4){0.f, 0.f, 0.f, 0.f};

    for (int kk = 0; kk < K; kk += 32) {
        // A tile: 512 16B-chunks, 1/thread
        {
            int r = tid >> 2, c = tid & 3;
            int grow = row0 + r; if (grow > M - 1) grow = M - 1;
            async_cp16(A + (size_t)grow * ldA + kk + c * 8, As + tid * 8);
        }
        // B tile: 1024 chunks, 2/thread
#pragma unroll
        for (int i = 0; i < 2; i++) {
            int chunk = i * 512 + tid;
            int r = chunk >> 2, c = chunk & 3;
            async_cp16(BT + (size_t)r * K + kk + c * 8, Bs + chunk * 8);
        }
        __syncthreads();

        const int koff = (lane >> 4) * 8;
        const int am = wm * 64 + (lane & 15);
        const int bn = wn * 64 + (lane & 15);
        bf16x8 af[4], bfr[4];
#pragma unroll
        for (int t = 0; t < 4; t++) {
            af[t]  = *(const bf16x8*)(As + (am + t * 16) * 32 + koff);
            bfr[t] = *(const bf16x8*)(Bs + (bn + t * 16) * 32 + koff);
        }
#pragma unroll
        for (int mt = 0; mt < 4; mt++)
#pragma unroll
            for (int nt = 0; nt < 4; nt++)
                acc[mt][nt] = __builtin_amdgcn_mfma_f32_16x16x32_bf16(
                    af[mt], bfr[nt], acc[mt][nt], 0, 0, 0);
        __syncthreads();
    }

    // epilogue: bias + relu (these GEMMs are all relu), bf16 (+fp8) stores
#pragma unroll
    for (int nt = 0; nt < 4; nt++) {
        int col = wn * 64 + nt * 16 + (lane & 15);
        float bv = bias[col];
#pragma unroll
        for (int mt = 0; mt < 4; mt++) {
            int rbase = row0 + wm * 64 + mt * 16 + ((lane >> 4) << 2);
#pragma unroll
            for (int reg = 0; reg < 4; reg++) {
                int row = rbase + reg;
                if (row < M) {
                    float v = fmaxf(acc[mt][nt][reg] + bv, 0.f);
                    out[(size_t)row * ldOut + col] = f2bf(v);
                    if (outF8 != nullptr) {
                        int pk = __builtin_amdgcn_cvt_pk_fp8_f32(v, v, 0, false);
                        outF8[(size_t)row * ldOut + col] = (u8)(pk & 0xff);
                    }
                }
            }
        }
    }
}

// ===========================================================================
// Narrow bf16 MFMA GEMM (m97, BK=32) — used only for the final concat GEMM
// with fused log_softmax. Aeff: A (k<Ksplit) / Acat (k>=Ksplit).
// ===========================================================================
__global__ __launch_bounds__(256, 3) void gemm_mfma(
    const u16* __restrict__ A, const u16* __restrict__ Acat, int Ksplit, int ldA,
    const u16* __restrict__ BT, const float* __restrict__ bias,
    float* __restrict__ out, int M, int K)
{
    __shared__ u16 As[128 * 32];
    __shared__ u16 Bs[128 * 32];

    const int tid = threadIdx.x;
    const int lane = tid & 63;
    const int wid = tid >> 6;
    const int wm = wid >> 1, wn = wid & 1;
    const int row0 = blockIdx.y * 128;

    f32x4 acc[4][4];
#pragma unroll
    for (int i = 0; i < 4; i++)
#pragma unroll
        for (int j = 0; j < 4; j++) acc[i][j] = (f32x4){0.f, 0.f, 0.f, 0.f};

    for (int kk = 0; kk < K; kk += 32) {
        const u16* Abase = (kk >= Ksplit) ? Acat : A;
        const int kbase = (kk >= Ksplit) ? (kk - Ksplit) : kk;
#pragma unroll
        for (int i = 0; i < 2; i++) {
            int chunk = i * 256 + tid;
            int r = chunk >> 2, c = chunk & 3;
            int grow = row0 + r; if (grow > M - 1) grow = M - 1;
            async_cp16(Abase + (size_t)grow * ldA + kbase + c * 8, As + chunk * 8);
        }
#pragma unroll
        for (int i = 0; i < 2; i++) {
            int chunk = i * 256 + tid;
            int r = chunk >> 2, c = chunk & 3;
            async_cp16(BT + (size_t)r * K + kk + c * 8, Bs + chunk * 8);
        }
        __syncthreads();

        const int koff = (lane >> 4) * 8;
        const int am = wm * 64 + (lane & 15);
        const int bn = wn * 64 + (lane & 15);
        bf16x8 af[4], bfr[4];
#pragma unroll
        for (int t = 0; t < 4; t++) {
            af[t]  = *(const bf16x8*)(As + (am + t * 16) * 32 + koff);
            bfr[t] = *(const bf16x8*)(Bs + (bn + t * 16) * 32 + koff);
        }
#pragma unroll
        for (int mt = 0; mt < 4; mt++)
#pragma unroll
            for (int nt = 0; nt < 4; nt++)
                acc[mt][nt] = __builtin_amdgcn_mfma_f32_16x16x32_bf16(
                    af[mt], bfr[nt], acc[mt][nt], 0, 0, 0);
        __syncthreads();
    }

    // fused log_softmax epilogue: cols 0..39 live in wn==0 waves
    if (wn != 0) return;
    const int quad = lane >> 4, li = lane & 15;
    float b0 = bias[li];
    float b1 = bias[16 + li];
    float b2 = (li < 8) ? bias[32 + li] : 0.f;
#pragma unroll
    for (int mt = 0; mt < 4; mt++) {
#pragma unroll
        for (int reg = 0; reg < 4; reg++) {
            int row = row0 + wm * 64 + mt * 16 + quad * 4 + reg;
            float v0 = acc[mt][0][reg] + b0;
            float v1 = acc[mt][1][reg] + b1;
            float v2 = (li < 8) ? (acc[mt][2][reg] + b2) : -INFINITY;
            float m = fmaxf(fmaxf(v0, v1), v2);
#pragma unroll
            for (int off = 1; off < 16; off <<= 1)
                m = fmaxf(m, __shfl_xor(m, off, 64));
            float s = expf(v0 - m) + expf(v1 - m)
                    + ((li < 8) ? expf(v2 - m) : 0.f);
#pragma unroll
            for (int off = 1; off < 16; off <<= 1)
                s += __shfl_xor(s, off, 64);
            float lg = m + logf(s);
            if (row < M) {
                out[(size_t)row * OUT_CH + li] = v0 - lg;
                out[(size_t)row * OUT_CH + 16 + li] = v1 - lg;
                if (li < 8) out[(size_t)row * OUT_CH + 32 + li] = v2 - lg;
            }
        }
    }
}

// ---------------------------------------------------------------------------
extern "C" void kernel_launch(void* const* d_in, const int* in_sizes, int n_in,
                              void* d_out, int out_size, void* d_ws, size_t ws_size,
                              hipStream_t stream)
{
    const float* x    = (const float*)d_in[0];
    const int*   ei   = (const int*)d_in[1];
    const float* W1a  = (const float*)d_in[2];
    const float* b1a  = (const float*)d_in[3];
    const float* W2a  = (const float*)d_in[4];
    const float* b2a  = (const float*)d_in[5];
    const float* W1b  = (const float*)d_in[6];
    const float* b1b  = (const float*)d_in[7];
    const float* W2b  = (const float*)d_in[8];
    const float* b2b  = (const float*)d_in[9];
    const float* Wlin = (const float*)d_in[10];
    const float* blin = (const float*)d_in[11];
    float* out = (float*)d_out;

    // ---- workspace carve-up (regions of 50000*256 bf16 = 25.6 MB) ----
    const size_t R = (size_t)N_NODES * HID;
    u16* R0 = (u16*)d_ws;          // xbf (first half) -> t2
    u16* R1 = R0 + R;              // partial-hist / zA (first half) + xf8 -> h1f8
    u16* R2 = R1 + R;              // t1 -> h2
    u16* R3 = R2 + R;              // h1 (live to end)
    u16* R4 = R3 + R;              // zB
    u16* xbf = R0;
    u16* zA  = R1;                                   // [50000,128] bf16
    u16* partial = (u16*)R1;                         // [512,6250] u16 = 6.4 MB (pre-gather_a)
    u8*  xf8 = (u8*)(R1 + (size_t)N_NODES * IN_CH);  // [50000,128] fp8 (2nd half)
    u8*  h1f8 = (u8*)R1;                             // [50000,256] fp8 (after zA dead)
    u16* t1  = R2;
    u16* h1  = R3;
    u16* zB  = R4;
    u16* t2  = R0;
    u16* h2  = R2;

    u16* wts = R4 + R;
    u16* W1aT = wts;                       // [256,128]
    u16* W2aT = W1aT + 256 * 128;          // [256,256]
    u16* W1bT = W2aT + 256 * 256;
    u16* W2bT = W1bT + 256 * 256;
    u16* WlinT = W2bT + 256 * 256;         // [128,512] (rows 40..127 zero)
    int* rowp   = (int*)(WlinT + 128 * 512);
    int* cursor = rowp + N_NODES;
    int* part   = cursor + N_NODES;
    u16* csr    = (u16*)(part + 64);       // [N_EDGES] u16 src ids
    u16* e16    = csr + N_EDGES;           // [2*N_EDGES] u16: src16 | dst16
    u16* src16  = e16;
    u16* dst16  = e16 + N_EDGES;

    dim3 blk(256);
    const int scanBlocks = (N_NODES + 1023) / 1024;  // 49
    const int aggBlocks  = (N_NODES + 3) / 4;        // 12500
    const int fillBlocks = 8 * ((N_EDGES + 2047) / 2048);
    const int gemmRows   = (N_NODES + 127) / 128;    // 391
    dim3 g1(1, gemmRows);

    // ---- prep (conversions + edge compress) then CSR build ----
    prep_fused<<<8965, blk, 0, stream>>>(x, xbf, xf8, ei, e16,
                                         W1a, W2a, W1b, W2b, Wlin,
                                         W1aT, W2aT, W1bT, W2bT, WlinT);
    hist_priv<<<8 * NCHUNK, blk, 0, stream>>>(dst16, partial);
    scan1<<<scanBlocks, blk, 0, stream>>>(partial, rowp, part);
    scan3<<<(N_NODES + 255) / 256, blk, 0, stream>>>(rowp, part, cursor, scanBlocks);
    csr_fill<<<fillBlocks, blk, 0, stream>>>(src16, dst16, cursor, csr);

    // ---- Layer a ----
    gather_agg_f8_128<<<aggBlocks, blk, 0, stream>>>(xbf, xf8, rowp, cursor, csr, zA);
    gemm_wide<<<gemmRows, 512, 0, stream>>>(zA, IN_CH, W1aT, b1a,
                                            t1, nullptr, N_NODES, IN_CH, HID);
    gemm_wide<<<gemmRows, 512, 0, stream>>>(t1, HID, W2aT, b2a,
                                            h1, h1f8, N_NODES, HID, HID);

    // ---- Layer b ----
    gather_agg_f8_256<<<aggBlocks, blk, 0, stream>>>(h1, h1f8, rowp, cursor, csr, zB);
    gemm_wide<<<gemmRows, 512, 0, stream>>>(zB, HID, W1bT, b1b,
                                            t2, nullptr, N_NODES, HID, HID);
    gemm_wide<<<gemmRows, 512, 0, stream>>>(t2, HID, W2bT, b2b,
                                            h2, nullptr, N_NODES, HID, HID);

    // ---- Final linear on [h1 | h2] + fused log_softmax -> d_out ----
    gemm_mfma<<<g1, blk, 0, stream>>>(h1, h2, HID, HID, WlinT, blin,
                                      out, N_NODES, 2 * HID);
}

// Round 13
// 348.004 us; speedup vs baseline: 1.1196x; 1.0119x over previous
//
#include <hip/hip_runtime.h>
#include <math.h>

// Problem constants
#define N_NODES 50000
#define N_EDGES 800000
#define IN_CH 128
#define HID 256
#define OUT_CH 40
#define GRP 6250          // nodes per dst-group (8 groups)
#define NCHUNK 64         // edge-chunks for histogram (8*64 = 512 blocks)
#define TS 264            // LDS t-tile row stride (u16): 256+8 breaks bank pow2

typedef unsigned short u16;
typedef unsigned char u8;
typedef __attribute__((ext_vector_type(8))) short bf16x8;
typedef __attribute__((ext_vector_type(4))) float f32x4;
typedef __attribute__((ext_vector_type(2))) float f32x2;

__device__ __forceinline__ float bf2f(u16 u) {
    union { unsigned int i; float f; } v; v.i = ((unsigned int)u) << 16; return v.f;
}
__device__ __forceinline__ u16 f2bf(float f) {   // round-to-nearest-even
    union { float f; unsigned int i; } v; v.f = f;
    unsigned int x = v.i;
    x += 0x7fffu + ((x >> 16) & 1u);
    return (u16)(x >> 16);
}

#define GLOBAL_AS __attribute__((address_space(1)))
#define LDS_AS __attribute__((address_space(3)))
__device__ __forceinline__ void async_cp16(const void* g, void* l) {
    __builtin_amdgcn_global_load_lds((const GLOBAL_AS unsigned int*)g,
                                     (LDS_AS unsigned int*)l, 16, 0, 0);
}

// ===========================================================================
// Fused prep (no LDS): x->{bf16,fp8} + weight transposes + u16 edge copies.
// Block ranges: [0,6250) conv_x; [6250,7813) edge-compress; [7813,8965) transposes.
// ===========================================================================
__device__ __forceinline__ void tr_one(
    const float* __restrict__ in, u16* __restrict__ out, int K, int N, int n)
{
    for (int k = threadIdx.x; k < K; k += 256) {
        float v = (n < N) ? in[(size_t)k * N + n] : 0.f;
        out[(size_t)n * K + k] = f2bf(v);
    }
}

__global__ __launch_bounds__(256) void prep_fused(
    const float* __restrict__ x, u16* __restrict__ xb, u8* __restrict__ xf8,
    const int* __restrict__ ei, u16* __restrict__ e16,
    const float* __restrict__ W1a, const float* __restrict__ W2a,
    const float* __restrict__ W1b, const float* __restrict__ W2b,
    const float* __restrict__ Wlin,
    u16* __restrict__ W1aT, u16* __restrict__ W2aT,
    u16* __restrict__ W1bT, u16* __restrict__ W2bT, u16* __restrict__ WlinT)
{
    int b = blockIdx.x;
    if (b < 6250) {
        int i = b * 256 + threadIdx.x;
        float4 v = ((const float4*)x)[i];
        ushort4 o;
        o.x = f2bf(v.x); o.y = f2bf(v.y); o.z = f2bf(v.z); o.w = f2bf(v.w);
        ((ushort4*)xb)[i] = o;
        int p = __builtin_amdgcn_cvt_pk_fp8_f32(v.x, v.y, 0, false);
        p = __builtin_amdgcn_cvt_pk_fp8_f32(v.z, v.w, p, true);
        ((unsigned int*)xf8)[i] = (unsigned int)p;
    } else if (b < 7813) {
        int i = (b - 6250) * 256 + threadIdx.x;
        if (i < (2 * N_EDGES) / 4) {
            int4 v = ((const int4*)ei)[i];
            ushort4 o;
            o.x = (u16)v.x; o.y = (u16)v.y; o.z = (u16)v.z; o.w = (u16)v.w;
            ((ushort4*)e16)[i] = o;
        }
    } else {
        int t = b - 7813;
        if (t < 256)       tr_one(W1a, W1aT, IN_CH, HID, t);
        else if (t < 512)  tr_one(W2a, W2aT, HID, HID, t - 256);
        else if (t < 768)  tr_one(W1b, W1bT, HID, HID, t - 512);
        else if (t < 1024) tr_one(W2b, W2bT, HID, HID, t - 768);
        else               tr_one(Wlin, WlinT, 2 * HID, OUT_CH, t - 1024);
    }
}

// ===========================================================================
// LDS-privatized degree histogram, u16 dst stream + u16 partial output.
// ===========================================================================
__global__ __launch_bounds__(256) void hist_priv(
    const u16* __restrict__ dst16, u16* __restrict__ partial)
{
    __shared__ int hist[GRP];     // 25 KB
    const int b = blockIdx.x;
    const int g = b & 7;
    const int sub = b >> 3;
    const int lo = g * GRP;
    const int CH = N_EDGES / NCHUNK;          // 12500
    for (int i = threadIdx.x; i < GRP; i += 256) hist[i] = 0;
    __syncthreads();
    const ushort4* dsts = (const ushort4*)(dst16 + sub * CH);
    for (int k = threadIdx.x; k < CH / 4; k += 256) {
        ushort4 d = dsts[k];
        int r0 = (int)d.x - lo, r1 = (int)d.y - lo;
        int r2 = (int)d.z - lo, r3 = (int)d.w - lo;
        if ((unsigned)r0 < (unsigned)GRP) atomicAdd(&hist[r0], 1);
        if ((unsigned)r1 < (unsigned)GRP) atomicAdd(&hist[r1], 1);
        if ((unsigned)r2 < (unsigned)GRP) atomicAdd(&hist[r2], 1);
        if ((unsigned)r3 < (unsigned)GRP) atomicAdd(&hist[r3], 1);
    }
    __syncthreads();
    u16* po = partial + (size_t)b * GRP;
    for (int i = threadIdx.x; i < GRP; i += 256) po[i] = (u16)hist[i];
}

// ===========================================================================
// scan1 + scan3: CSR row_ptr build
// ===========================================================================
__global__ __launch_bounds__(256) void scan1(
    const u16* __restrict__ partial, int* __restrict__ excl,
    int* __restrict__ partials_out)
{
    __shared__ int lds[256];
    const int tid = threadIdx.x;
    const int base = blockIdx.x * 1024 + tid * 4;
    int v[4]; int s = 0;
#pragma unroll
    for (int i = 0; i < 4; i++) {
        int idx = base + i;
        int d = 0;
        if (idx < N_NODES) {
            int g = idx / GRP;
            int off = idx - g * GRP;
#pragma unroll
            for (int sub = 0; sub < NCHUNK; sub++)
                d += partial[(size_t)(sub * 8 + g) * GRP + off];
        }
        v[i] = d;
        s += d;
    }
    lds[tid] = s;
    __syncthreads();
    for (int off = 1; off < 256; off <<= 1) {
        int t = (tid >= off) ? lds[tid - off] : 0;
        __syncthreads();
        lds[tid] += t;
        __syncthreads();
    }
    int run = lds[tid] - s;
#pragma unroll
    for (int i = 0; i < 4; i++) {
        int idx = base + i;
        if (idx < N_NODES) excl[idx] = run;
        run += v[i];
    }
    if (tid == 255) partials_out[blockIdx.x] = lds[255];
}

__global__ __launch_bounds__(256) void scan3(
    int* __restrict__ excl, const int* __restrict__ partials,
    int* __restrict__ cursor, int nPart)
{
    __shared__ int bp[64];
    const int tid = threadIdx.x;
    if (tid < 64) {
        int orig = (tid < nPart) ? partials[tid] : 0;
        int v = orig;
#pragma unroll
        for (int off = 1; off < 64; off <<= 1) {
            int t = __shfl_up(v, off, 64);
            if (tid >= off) v += t;
        }
        bp[tid] = v - orig;
    }
    __syncthreads();
    int idx = blockIdx.x * 256 + tid;
    if (idx < N_NODES) {
        int r = excl[idx] + bp[idx >> 10];
        excl[idx] = r;
        cursor[idx] = r;
    }
}

// Dst-sharded fill on u16 edge copies.
__global__ __launch_bounds__(256) void csr_fill(
    const u16* __restrict__ src16, const u16* __restrict__ dst16,
    int* __restrict__ cursor, u16* __restrict__ csr_src)
{
    const int g = blockIdx.x & 7;
    const int c = blockIdx.x >> 3;
    const int lo = g * GRP, hi = lo + GRP;
    const int base = c * 2048;
#pragma unroll
    for (int i = 0; i < 8; i++) {
        int e = base + i * 256 + threadIdx.x;
        if (e < N_EDGES) {
            int d = dst16[e];
            if (d >= lo && d < hi) {
                int pos = atomicAdd(&cursor[d], 1);
                csr_src[pos] = src16[e];
            }
        }
    }
}

// ===========================================================================
// Gather aggregation, fp8 neighbor table + bf16 self term, fp32 accumulate.
// ===========================================================================
__global__ __launch_bounds__(256) void gather_agg_f8_128(
    const u16* __restrict__ feat_bf, const u8* __restrict__ feat_f8,
    const int* __restrict__ row_ptr, const int* __restrict__ row_end,
    const u16* __restrict__ csr_src, u16* __restrict__ out)
{
    int node = (blockIdx.x * 256 + threadIdx.x) >> 6;
    int lane = threadIdx.x & 63;
    if (node >= N_NODES) return;
    ushort2 sv = ((const ushort2*)(feat_bf + (size_t)node * IN_CH))[lane];
    float ax = bf2f(sv.x), ay = bf2f(sv.y);
    int j = row_ptr[node], e = row_end[node];
    for (; j + 4 <= e; j += 4) {
        int s0 = csr_src[j], s1 = csr_src[j + 1];
        int s2 = csr_src[j + 2], s3 = csr_src[j + 3];
        int v0 = ((const u16*)(feat_f8 + (size_t)s0 * IN_CH))[lane];
        int v1 = ((const u16*)(feat_f8 + (size_t)s1 * IN_CH))[lane];
        int v2 = ((const u16*)(feat_f8 + (size_t)s2 * IN_CH))[lane];
        int v3 = ((const u16*)(feat_f8 + (size_t)s3 * IN_CH))[lane];
        f32x2 d0 = __builtin_amdgcn_cvt_pk_f32_fp8(v0, false);
        f32x2 d1 = __builtin_amdgcn_cvt_pk_f32_fp8(v1, false);
        f32x2 d2 = __builtin_amdgcn_cvt_pk_f32_fp8(v2, false);
        f32x2 d3 = __builtin_amdgcn_cvt_pk_f32_fp8(v3, false);
        ax += (d0.x + d1.x) + (d2.x + d3.x);
        ay += (d0.y + d1.y) + (d2.y + d3.y);
    }
    for (; j < e; j++) {
        int sa = csr_src[j];
        int va = ((const u16*)(feat_f8 + (size_t)sa * IN_CH))[lane];
        f32x2 da = __builtin_amdgcn_cvt_pk_f32_fp8(va, false);
        ax += da.x; ay += da.y;
    }
    ushort2 o; o.x = f2bf(ax); o.y = f2bf(ay);
    ((ushort2*)(out + (size_t)node * IN_CH))[lane] = o;
}

__global__ __launch_bounds__(256) void gather_agg_f8_256(
    const u16* __restrict__ feat_bf, const u8* __restrict__ feat_f8,
    const int* __restrict__ row_ptr, const int* __restrict__ row_end,
    const u16* __restrict__ csr_src, u16* __restrict__ out)
{
    int node = (blockIdx.x * 256 + threadIdx.x) >> 6;
    int lane = threadIdx.x & 63;
    if (node >= N_NODES) return;
    ushort4 sv = ((const ushort4*)(feat_bf + (size_t)node * HID))[lane];
    float ax = bf2f(sv.x), ay = bf2f(sv.y), az = bf2f(sv.z), aw = bf2f(sv.w);
    int j = row_ptr[node], e = row_end[node];
    for (; j + 4 <= e; j += 4) {
        int s0 = csr_src[j], s1 = csr_src[j + 1];
        int s2 = csr_src[j + 2], s3 = csr_src[j + 3];
        int v0 = ((const int*)(feat_f8 + (size_t)s0 * HID))[lane];
        int v1 = ((const int*)(feat_f8 + (size_t)s1 * HID))[lane];
        int v2 = ((const int*)(feat_f8 + (size_t)s2 * HID))[lane];
        int v3 = ((const int*)(feat_f8 + (size_t)s3 * HID))[lane];
        f32x2 l0 = __builtin_amdgcn_cvt_pk_f32_fp8(v0, false);
        f32x2 h0 = __builtin_amdgcn_cvt_pk_f32_fp8(v0, true);
        f32x2 l1 = __builtin_amdgcn_cvt_pk_f32_fp8(v1, false);
        f32x2 h1v = __builtin_amdgcn_cvt_pk_f32_fp8(v1, true);
        f32x2 l2 = __builtin_amdgcn_cvt_pk_f32_fp8(v2, false);
        f32x2 h2v = __builtin_amdgcn_cvt_pk_f32_fp8(v2, true);
        f32x2 l3 = __builtin_amdgcn_cvt_pk_f32_fp8(v3, false);
        f32x2 h3 = __builtin_amdgcn_cvt_pk_f32_fp8(v3, true);
        ax += (l0.x + l1.x) + (l2.x + l3.x);
        ay += (l0.y + l1.y) + (l2.y + l3.y);
        az += (h0.x + h1v.x) + (h2v.x + h3.x);
        aw += (h0.y + h1v.y) + (h2v.y + h3.y);
    }
    for (; j < e; j++) {
        int sa = csr_src[j];
        int va = ((const int*)(feat_f8 + (size_t)sa * HID))[lane];
        f32x2 la = __builtin_amdgcn_cvt_pk_f32_fp8(va, false);
        f32x2 ha = __builtin_amdgcn_cvt_pk_f32_fp8(va, true);
        ax += la.x; ay += la.y; az += ha.x; aw += ha.y;
    }
    ushort4 o;
    o.x = f2bf(ax); o.y = f2bf(ay); o.z = f2bf(az); o.w = f2bf(aw);
    ((ushort4*)(out + (size_t)node * HID))[lane] = o;
}

// ===========================================================================
// Fused 2-layer MLP: out = relu( relu(A@W1T^T + b1) @ W2T^T + b2 )
// A [M,K1] bf16; W1T [256,K1]; W2T [256,256]; out [M,256] bf16 (+fp8 copy).
// Block: 256 thr = 4 waves, tile 64 rows x 256 cols (full hidden width!) —
// t never touches HBM: parked in padded LDS (stride 264 u16 -> 2-way banks).
// LDS 4+16+33 = 53 KB -> 3 blocks/CU.
// ===========================================================================
__global__ __launch_bounds__(256, 3) void mlp_fused(
    const u16* __restrict__ A, int K1,
    const u16* __restrict__ W1T, const float* __restrict__ b1,
    const u16* __restrict__ W2T, const float* __restrict__ b2,
    u16* __restrict__ out, u8* __restrict__ outF8, int M)
{
    __shared__ u16 As[64 * 32];    // 4 KB
    __shared__ u16 Ws[256 * 32];   // 16 KB (W1 then W2 chunks)
    __shared__ u16 Ts[64 * TS];    // 33 KB t-tile

    const int tid = threadIdx.x;
    const int lane = tid & 63;
    const int wid = tid >> 6;            // col-wave 0..3
    const int li = lane & 15;
    const int quad = lane >> 4;
    const int koff = quad * 8;
    const int row0 = blockIdx.x * 64;

    f32x4 acc[4][4];
#pragma unroll
    for (int i = 0; i < 4; i++)
#pragma unroll
        for (int j = 0; j < 4; j++) acc[i][j] = (f32x4){0.f, 0.f, 0.f, 0.f};

    // ---- phase 1: t = A @ W1 ----
    for (int kk = 0; kk < K1; kk += 32) {
        {   // A tile 64x32: 256 chunks, 1/thread
            int r = tid >> 2, c = tid & 3;
            int grow = row0 + r; if (grow > M - 1) grow = M - 1;
            async_cp16(A + (size_t)grow * K1 + kk + c * 8, As + tid * 8);
        }
#pragma unroll
        for (int i = 0; i < 4; i++) {   // W1 tile 256x32: 1024 chunks
            int chunk = i * 256 + tid;
            int r = chunk >> 2, c = chunk & 3;
            async_cp16(W1T + (size_t)r * K1 + kk + c * 8, Ws + chunk * 8);
        }
        __syncthreads();
        bf16x8 af[4], bfr[4];
#pragma unroll
        for (int t = 0; t < 4; t++) {
            af[t]  = *(const bf16x8*)(As + (t * 16 + li) * 32 + koff);
            bfr[t] = *(const bf16x8*)(Ws + (wid * 64 + t * 16 + li) * 32 + koff);
        }
#pragma unroll
        for (int mt = 0; mt < 4; mt++)
#pragma unroll
            for (int nt = 0; nt < 4; nt++)
                acc[mt][nt] = __builtin_amdgcn_mfma_f32_16x16x32_bf16(
                    af[mt], bfr[nt], acc[mt][nt], 0, 0, 0);
        __syncthreads();
    }

    // bias+relu -> bf16 t-tile in LDS (C/D layout scatter; u16 stores)
#pragma unroll
    for (int nt = 0; nt < 4; nt++) {
        int col = wid * 64 + nt * 16 + li;
        float bv = b1[col];
#pragma unroll
        for (int mt = 0; mt < 4; mt++) {
#pragma unroll
            for (int reg = 0; reg < 4; reg++) {
                int row = mt * 16 + quad * 4 + reg;
                float v = fmaxf(acc[mt][nt][reg] + bv, 0.f);
                Ts[row * TS + col] = f2bf(v);
                acc[mt][nt][reg] = 0.f;   // re-zero for phase 2
            }
        }
    }
    __syncthreads();

    // ---- phase 2: h = t @ W2 ----
    for (int kk = 0; kk < HID; kk += 32) {
#pragma unroll
        for (int i = 0; i < 4; i++) {   // W2 tile 256x32
            int chunk = i * 256 + tid;
            int r = chunk >> 2, c = chunk & 3;
            async_cp16(W2T + (size_t)r * HID + kk + c * 8, Ws + chunk * 8);
        }
        __syncthreads();
        bf16x8 af[4], bfr[4];
#pragma unroll
        for (int t = 0; t < 4; t++) {
            af[t]  = *(const bf16x8*)(Ts + (t * 16 + li) * TS + kk + koff);
            bfr[t] = *(const bf16x8*)(Ws + (wid * 64 + t * 16 + li) * 32 + koff);
        }
#pragma unroll
        for (int mt = 0; mt < 4; mt++)
#pragma unroll
            for (int nt = 0; nt < 4; nt++)
                acc[mt][nt] = __builtin_amdgcn_mfma_f32_16x16x32_bf16(
                    af[mt], bfr[nt], acc[mt][nt], 0, 0, 0);
        __syncthreads();
    }

    // ---- epilogue: bias + relu, bf16 (+fp8) stores ----
#pragma unroll
    for (int nt = 0; nt < 4; nt++) {
        int col = wid * 64 + nt * 16 + li;
        float bv = b2[col];
#pragma unroll
        for (int mt = 0; mt < 4; mt++) {
            int rbase = row0 + mt * 16 + quad * 4;
#pragma unroll
            for (int reg = 0; reg < 4; reg++) {
                int row = rbase + reg;
                if (row < M) {
                    float v = fmaxf(acc[mt][nt][reg] + bv, 0.f);
                    out[(size_t)row * HID + col] = f2bf(v);
                    if (outF8 != nullptr) {
                        int pk = __builtin_amdgcn_cvt_pk_fp8_f32(v, v, 0, false);
                        outF8[(size_t)row * HID + col] = (u8)(pk & 0xff);
                    }
                }
            }
        }
    }
}

// ===========================================================================
// Narrow bf16 MFMA GEMM (m97, BK=32) — final concat GEMM + fused log_softmax.
// ===========================================================================
__global__ __launch_bounds__(256, 3) void gemm_mfma(
    const u16* __restrict__ A, const u16* __restrict__ Acat, int Ksplit, int ldA,
    const u16* __restrict__ BT, const float* __restrict__ bias,
    float* __restrict__ out, int M, int K)
{
    __shared__ u16 As[128 * 32];
    __shared__ u16 Bs[128 * 32];

    const int tid = threadIdx.x;
    const int lane = tid & 63;
    const int wid = tid >> 6;
    const int wm = wid >> 1, wn = wid & 1;
    const int row0 = blockIdx.y * 128;

    f32x4 acc[4][4];
#pragma unroll
    for (int i = 0; i < 4; i++)
#pragma unroll
        for (int j = 0; j < 4; j++) acc[i][j] = (f32x4){0.f, 0.f, 0.f, 0.f};

    for (int kk = 0; kk < K; kk += 32) {
        const u16* Abase = (kk >= Ksplit) ? Acat : A;
        const int kbase = (kk >= Ksplit) ? (kk - Ksplit) : kk;
#pragma unroll
        for (int i = 0; i < 2; i++) {
            int chunk = i * 256 + tid;
            int r = chunk >> 2, c = chunk & 3;
            int grow = row0 + r; if (grow > M - 1) grow = M - 1;
            async_cp16(Abase + (size_t)grow * ldA + kbase + c * 8, As + chunk * 8);
        }
#pragma unroll
        for (int i = 0; i < 2; i++) {
            int chunk = i * 256 + tid;
            int r = chunk >> 2, c = chunk & 3;
            async_cp16(BT + (size_t)r * K + kk + c * 8, Bs + chunk * 8);
        }
        __syncthreads();

        const int koff = (lane >> 4) * 8;
        const int am = wm * 64 + (lane & 15);
        const int bn = wn * 64 + (lane & 15);
        bf16x8 af[4], bfr[4];
#pragma unroll
        for (int t = 0; t < 4; t++) {
            af[t]  = *(const bf16x8*)(As + (am + t * 16) * 32 + koff);
            bfr[t] = *(const bf16x8*)(Bs + (bn + t * 16) * 32 + koff);
        }
#pragma unroll
        for (int mt = 0; mt < 4; mt++)
#pragma unroll
            for (int nt = 0; nt < 4; nt++)
                acc[mt][nt] = __builtin_amdgcn_mfma_f32_16x16x32_bf16(
                    af[mt], bfr[nt], acc[mt][nt], 0, 0, 0);
        __syncthreads();
    }

    if (wn != 0) return;
    const int quad = lane >> 4, li = lane & 15;
    float b0 = bias[li];
    float b1 = bias[16 + li];
    float b2 = (li < 8) ? bias[32 + li] : 0.f;
#pragma unroll
    for (int mt = 0; mt < 4; mt++) {
#pragma unroll
        for (int reg = 0; reg < 4; reg++) {
            int row = row0 + wm * 64 + mt * 16 + quad * 4 + reg;
            float v0 = acc[mt][0][reg] + b0;
            float v1 = acc[mt][1][reg] + b1;
            float v2 = (li < 8) ? (acc[mt][2][reg] + b2) : -INFINITY;
            float m = fmaxf(fmaxf(v0, v1), v2);
#pragma unroll
            for (int off = 1; off < 16; off <<= 1)
                m = fmaxf(m, __shfl_xor(m, off, 64));
            float s = expf(v0 - m) + expf(v1 - m)
                    + ((li < 8) ? expf(v2 - m) : 0.f);
#pragma unroll
            for (int off = 1; off < 16; off <<= 1)
                s += __shfl_xor(s, off, 64);
            float lg = m + logf(s);
            if (row < M) {
                out[(size_t)row * OUT_CH + li] = v0 - lg;
                out[(size_t)row * OUT_CH + 16 + li] = v1 - lg;
                if (li < 8) out[(size_t)row * OUT_CH + 32 + li] = v2 - lg;
            }
        }
    }
}

// ---------------------------------------------------------------------------
extern "C" void kernel_launch(void* const* d_in, const int* in_sizes, int n_in,
                              void* d_out, int out_size, void* d_ws, size_t ws_size,
                              hipStream_t stream)
{
    const float* x    = (const float*)d_in[0];
    const int*   ei   = (const int*)d_in[1];
    const float* W1a  = (const float*)d_in[2];
    const float* b1a  = (const float*)d_in[3];
    const float* W2a  = (const float*)d_in[4];
    const float* b2a  = (const float*)d_in[5];
    const float* W1b  = (const float*)d_in[6];
    const float* b1b  = (const float*)d_in[7];
    const float* W2b  = (const float*)d_in[8];
    const float* b2b  = (const float*)d_in[9];
    const float* Wlin = (const float*)d_in[10];
    const float* blin = (const float*)d_in[11];
    float* out = (float*)d_out;

    // ---- workspace carve-up (regions of 50000*256 bf16 = 25.6 MB) ----
    const size_t R = (size_t)N_NODES * HID;
    u16* R0 = (u16*)d_ws;          // xbf
    u16* R1 = R0 + R;              // partial-hist / zA (1st half) + xf8 (2nd) -> h1f8
    u16* R2 = R1 + R;              // h2
    u16* R3 = R2 + R;              // h1 (live to end)
    u16* R4 = R3 + R;              // zB
    u16* xbf = R0;
    u16* zA  = R1;                                   // [50000,128] bf16
    u16* partial = (u16*)R1;                         // [512,6250] u16 (pre-gather_a)
    u8*  xf8 = (u8*)(R1 + (size_t)N_NODES * IN_CH);  // [50000,128] fp8
    u8*  h1f8 = (u8*)R1;                             // [50000,256] fp8 (rows written only
                                                     //  after the same rows of zA consumed)
    u16* h1  = R3;
    u16* zB  = R4;
    u16* h2  = R2;

    u16* wts = R4 + R;
    u16* W1aT = wts;                       // [256,128]
    u16* W2aT = W1aT + 256 * 128;          // [256,256]
    u16* W1bT = W2aT + 256 * 256;
    u16* W2bT = W1bT + 256 * 256;
    u16* WlinT = W2bT + 256 * 256;         // [128,512] (rows 40..127 zero)
    int* rowp   = (int*)(WlinT + 128 * 512);
    int* cursor = rowp + N_NODES;
    int* part   = cursor + N_NODES;
    u16* csr    = (u16*)(part + 64);       // [N_EDGES] u16 src ids
    u16* e16    = csr + N_EDGES;           // [2*N_EDGES] u16: src16 | dst16
    u16* src16  = e16;
    u16* dst16  = e16 + N_EDGES;

    dim3 blk(256);
    const int scanBlocks = (N_NODES + 1023) / 1024;  // 49
    const int aggBlocks  = (N_NODES + 3) / 4;        // 12500
    const int fillBlocks = 8 * ((N_EDGES + 2047) / 2048);
    const int mlpBlocks  = (N_NODES + 63) / 64;      // 782
    dim3 g1(1, (N_NODES + 127) / 128);

    // ---- prep + CSR build ----
    prep_fused<<<8965, blk, 0, stream>>>(x, xbf, xf8, ei, e16,
                                         W1a, W2a, W1b, W2b, Wlin,
                                         W1aT, W2aT, W1bT, W2bT, WlinT);
    hist_priv<<<8 * NCHUNK, blk, 0, stream>>>(dst16, partial);
    scan1<<<scanBlocks, blk, 0, stream>>>(partial, rowp, part);
    scan3<<<(N_NODES + 255) / 256, blk, 0, stream>>>(rowp, part, cursor, scanBlocks);
    csr_fill<<<fillBlocks, blk, 0, stream>>>(src16, dst16, cursor, csr);

    // ---- Layer a: gather + fused MLP (zA -> h1, + fp8 table) ----
    gather_agg_f8_128<<<aggBlocks, blk, 0, stream>>>(xbf, xf8, rowp, cursor, csr, zA);
    mlp_fused<<<mlpBlocks, blk, 0, stream>>>(zA, IN_CH, W1aT, b1a, W2aT, b2a,
                                             h1, h1f8, N_NODES);

    // ---- Layer b: gather + fused MLP (zB -> h2) ----
    gather_agg_f8_256<<<aggBlocks, blk, 0, stream>>>(h1, h1f8, rowp, cursor, csr, zB);
    mlp_fused<<<mlpBlocks, blk, 0, stream>>>(zB, HID, W1bT, b1b, W2bT, b2b,
                                             h2, nullptr, N_NODES);

    // ---- Final linear on [h1 | h2] + fused log_softmax -> d_out ----
    gemm_mfma<<<g1, blk, 0, stream>>>(h1, h2, HID, HID, WlinT, blin,
                                      out, N_NODES, 2 * HID);
}